// Round 7
// baseline (410.200 us; speedup 1.0000x reference)
//
#include <hip/hip_runtime.h>
#include <hip/hip_bf16.h>
#include <stdint.h>

using bf16 = __hip_bfloat16;
typedef __attribute__((ext_vector_type(8))) short bf16x8;
typedef __attribute__((ext_vector_type(4))) float f32x4;
typedef __attribute__((ext_vector_type(8))) unsigned short ushort8;

#define MFMA16(a,b,c) __builtin_amdgcn_mfma_f32_16x16x32_bf16(a,b,c,0,0,0)

static constexpr int Bc = 4, Sc = 2048, HSc = 2048, Hc = 16, KVc = 8, Dc = 128;

__device__ __forceinline__ void gl_lds16(const void* g, void* l) {
  __builtin_amdgcn_global_load_lds((const __attribute__((address_space(1))) uint32_t*)g,
                                   (__attribute__((address_space(3))) uint32_t*)l, 16, 0, 0);
}

__device__ __forceinline__ unsigned short f2bf(float f) {
  bf16 h = __float2bfloat16(f);
  return *reinterpret_cast<unsigned short*>(&h);
}

// ---------------- fused fp32 -> bf16 convert ----------------
__global__ __launch_bounds__(256) void cvt_all(const float* __restrict__ x,
                                               const float* __restrict__ wq,
                                               const float* __restrict__ wk,
                                               const float* __restrict__ wv,
                                               const float* __restrict__ wo,
                                               unsigned short* __restrict__ xb,
                                               unsigned short* __restrict__ wqkv,
                                               unsigned short* __restrict__ wob) {
  const int NX = 2097152, NQ = 524288, NK = 262144, NV = 262144, NO = 524288;
  const int T = NX + NQ + NK + NV + NO;
  int stride = gridDim.x * blockDim.x;
  for (int i = blockIdx.x * blockDim.x + threadIdx.x; i < T; i += stride) {
    const float* s;
    unsigned short* d;
    int j = i;
    if (j < NX) { s = x; d = xb; }
    else if ((j -= NX) < NQ) { s = wq; d = wqkv; }
    else if ((j -= NQ) < NK) { s = wk; d = wqkv + (size_t)NQ * 8; }
    else if ((j -= NK) < NV) { s = wv; d = wqkv + (size_t)(NQ + NK) * 8; }
    else { j -= NV; s = wo; d = wob; }
    const float4 a = *(const float4*)(s + (size_t)j * 8);
    const float4 b = *(const float4*)(s + (size_t)j * 8 + 4);
    ushort8 o;
    o[0] = f2bf(a.x); o[1] = f2bf(a.y); o[2] = f2bf(a.z); o[3] = f2bf(a.w);
    o[4] = f2bf(b.x); o[5] = f2bf(b.y); o[6] = f2bf(b.z); o[7] = f2bf(b.w);
    *(ushort8*)(d + (size_t)j * 8) = o;
  }
}

__device__ __forceinline__ void storeC(float* C, size_t i, float v) { C[i] = v; }
__device__ __forceinline__ void storeC(bf16* C, size_t i, float v) { C[i] = __float2bfloat16(v); }

// ---------------- 256x256 8-phase GEMM (unchanged from round 5) ----------------
#define LDA_(MI, BUF)                                                          \
  _Pragma("unroll") for (int rf = 0; rf < 4; ++rf)                             \
  _Pragma("unroll") for (int k = 0; k < 2; ++k) {                              \
    const int row_ = (MI * 4 + rf) * 16 + lr;                                  \
    a[rf][k] = *(const bf16x8*)&sA[BUF][wm][row_][((k * 4 + lg) ^ (row_ & 7)) * 8]; \
  }
#define LDB_(NI, BUF, BREG)                                                    \
  _Pragma("unroll") for (int j = 0; j < 2; ++j)                                \
  _Pragma("unroll") for (int k = 0; k < 2; ++k) {                              \
    const int row_ = (bco + NI * 2 + j) * 16 + lr;                             \
    BREG[j][k] = *(const bf16x8*)&sB[BUF][bh][row_][((k * 4 + lg) ^ (row_ & 7)) * 8]; \
  }
#define MM_(MI, NI, BREG)                                                      \
  __builtin_amdgcn_s_setprio(1);                                               \
  _Pragma("unroll") for (int rf = 0; rf < 4; ++rf)                             \
  _Pragma("unroll") for (int j = 0; j < 2; ++j)                                \
  _Pragma("unroll") for (int k = 0; k < 2; ++k)                                \
    acc[MI * 4 + rf][NI * 2 + j] =                                             \
        MFMA16(a[rf][k], BREG[j][k], acc[MI * 4 + rf][NI * 2 + j]);            \
  __builtin_amdgcn_s_setprio(0);
#define BAR_ __builtin_amdgcn_s_barrier();
#define VM4_ asm volatile("s_waitcnt vmcnt(4)" ::: "memory");
#define VM0_ asm volatile("s_waitcnt vmcnt(0)" ::: "memory");

template <typename OUT_T>
__global__ __launch_bounds__(512, 2) void gemm8(const bf16* __restrict__ A,
                                                const bf16* __restrict__ B,
                                                OUT_T* __restrict__ C,
                                                int M, int N, int K,
                                                int gm, int gn, int rbm, int rbn) {
  const int nwg = gridDim.x;
  const int cpx = nwg >> 3;
  const int swz = (blockIdx.x & 7) * cpx + (blockIdx.x >> 3);
  const int rsz = rbm * rbn;
  const int region = swz / rsz, rid = swz % rsz;
  const int regions_n = gn / rbn;
  const int bm = (region / regions_n) * rbm + rid / rbn;
  const int bn = (region % regions_n) * rbn + rid % rbn;

  __shared__ __align__(16) bf16 sA[2][2][128][64];
  __shared__ __align__(16) bf16 sB[2][2][128][64];

  const int tid = threadIdx.x;
  const int lane = tid & 63;
  const int wave = tid >> 6;
  const int wm = wave >> 2;
  const int wn = wave & 3;
  const int lg = lane >> 4, lr = lane & 15;
  const int bh = wn >> 1;
  const int bco = (wn & 1) * 4;

  const int rowA = bm * 256;
  const int colB = bn * 256;
  const int NT = K >> 6;

  f32x4 acc[8][4];
  #pragma unroll
  for (int i = 0; i < 8; ++i)
    #pragma unroll
    for (int j = 0; j < 4; ++j) acc[i][j] = (f32x4){0.f, 0.f, 0.f, 0.f};

  auto stA = [&](int buf, int half, int kt) {
    const bf16* src = A + (size_t)(rowA + half * 128) * K + kt * 64;
    #pragma unroll
    for (int is = 0; is < 2; ++is) {
      int r = is * 64 + (tid >> 3);
      int sl = (tid & 7) ^ (r & 7);
      gl_lds16(src + (size_t)r * K + sl * 8, &sA[buf][half][r][(tid & 7) * 8]);
    }
  };
  auto stB = [&](int buf, int half, int kt) {
    const bf16* src = B + (size_t)(colB + half * 128) * K + kt * 64;
    #pragma unroll
    for (int is = 0; is < 2; ++is) {
      int r = is * 64 + (tid >> 3);
      int sl = (tid & 7) ^ (r & 7);
      gl_lds16(src + (size_t)r * K + sl * 8, &sB[buf][half][r][(tid & 7) * 8]);
    }
  };

  stB(0, 0, 0); stB(0, 1, 0); stA(0, 0, 0); stA(0, 1, 0);
  stB(1, 0, 1); stB(1, 1, 1);
  VM4_
  __builtin_amdgcn_s_barrier();

  for (int t = 0; t < NT; t += 2) {
    const bool lastit = (t + 2 >= NT);
    bf16x8 a[4][2], bl[2][2], br[2][2];
    // ---------- K-tile t (buf0) ----------
    LDA_(0, 0) LDB_(0, 0, bl)
    stA(1, 0, t + 1);
    BAR_ MM_(0, 0, bl) BAR_
    LDB_(1, 0, br)
    stA(1, 1, t + 1);
    BAR_ MM_(0, 1, br) BAR_
    LDA_(1, 0)
    if (!lastit) stB(0, 0, t + 2);
    BAR_ MM_(1, 0, bl) BAR_
    if (!lastit) stB(0, 1, t + 2);
    BAR_ MM_(1, 1, br)
    if (lastit) { VM0_ } else { VM4_ }
    BAR_
    // ---------- K-tile t+1 (buf1) ----------
    LDA_(0, 1) LDB_(0, 1, bl)
    if (!lastit) stA(0, 0, t + 2);
    BAR_ MM_(0, 0, bl) BAR_
    LDB_(1, 1, br)
    if (!lastit) stA(0, 1, t + 2);
    BAR_ MM_(0, 1, br) BAR_
    LDA_(1, 1)
    if (t + 3 < NT) stB(1, 0, t + 3);
    BAR_ MM_(1, 0, bl) BAR_
    if (t + 3 < NT) stB(1, 1, t + 3);
    BAR_ MM_(1, 1, br)
    if (!lastit) { VM4_ }
    BAR_
  }

  #pragma unroll
  for (int rf = 0; rf < 8; ++rf)
    #pragma unroll
    for (int cf = 0; cf < 4; ++cf)
      #pragma unroll
      for (int r = 0; r < 4; ++r) {
        size_t row = rowA + wm * 128 + rf * 16 + lg * 4 + r;
        size_t col = colB + wn * 64 + cf * 16 + lr;
        storeC(C, row * (size_t)N + col, acc[rf][cf][r]);
      }
}

// ---------------- RMSNorm + RoPE on Q and K (Q pre-scaled by 1/sqrt(D)*log2e) ----------------
__global__ __launch_bounds__(256) void norm_rope(const bf16* __restrict__ qkv,
                                                 const float* __restrict__ cosT,
                                                 const float* __restrict__ sinT,
                                                 const float* __restrict__ qw,
                                                 const float* __restrict__ kw,
                                                 bf16* __restrict__ Qn, bf16* __restrict__ Kn) {
  const int bs = blockIdx.x;
  const int s = bs & (Sc - 1);
  const int b = bs >> 11;
  const int wave = threadIdx.x >> 6, lane = threadIdx.x & 63;
  const float QSCL = 0.08838834764831845f * 1.4426950408889634f;
  const float c0 = cosT[(size_t)s * Dc + lane];
  const float c1 = cosT[(size_t)s * Dc + 64 + lane];
  const float s0 = sinT[(size_t)s * Dc + lane];
  const float s1 = sinT[(size_t)s * Dc + 64 + lane];
  const bf16* row = qkv + (size_t)bs * 4096;
  #pragma unroll
  for (int i = 0; i < 6; ++i) {
    int head = wave * 6 + i;
    bool isQ = head < 16;
    int col = head * Dc;
    float x0 = __bfloat162float(row[col + lane]);
    float x1 = __bfloat162float(row[col + 64 + lane]);
    float ss = x0 * x0 + x1 * x1;
    #pragma unroll
    for (int off = 32; off; off >>= 1) ss += __shfl_xor(ss, off);
    float inv = rsqrtf(ss * (1.0f / 128.0f) + 1e-6f);
    const float* w = isQ ? qw : kw;
    float n0 = x0 * inv * w[lane];
    float n1 = x1 * inv * w[lane + 64];
    float o0 = n0 * c0 - n1 * s0;
    float o1 = n1 * c1 + n0 * s1;
    if (isQ) { o0 *= QSCL; o1 *= QSCL; }
    size_t base;
    bf16* dst;
    if (isQ) { base = ((size_t)(b * Hc + head) * Sc + s) * Dc; dst = Qn; }
    else     { base = ((size_t)(b * KVc + (head - 16)) * Sc + s) * Dc; dst = Kn; }
    dst[base + lane] = __float2bfloat16(o0);
    dst[base + 64 + lane] = __float2bfloat16(o1);
  }
}

// ---------------- V transpose: qkv V slice -> Vt [B][KV][D][S] ----------------
__global__ __launch_bounds__(256) void v_transpose(const bf16* __restrict__ qkv,
                                                   bf16* __restrict__ Vt) {
  const int s0 = blockIdx.x * 64;
  const int bk = blockIdx.y;
  __shared__ __align__(16) bf16 tile[64][136];
  const int tid = threadIdx.x;
  const size_t srcbase = ((size_t)(bk >> 3) * Sc + s0) * 4096 + 3072 + (size_t)(bk & 7) * Dc;
  #pragma unroll
  for (int it = 0; it < 4; ++it) {
    int idx = it * 256 + tid;
    int r = idx >> 4, ch = idx & 15;
    *(bf16x8*)&tile[r][ch * 8] = *(const bf16x8*)(qkv + srcbase + (size_t)r * 4096 + ch * 8);
  }
  __syncthreads();
  const size_t dstbase = (size_t)bk * Dc * Sc + s0;
  #pragma unroll
  for (int it = 0; it < 4; ++it) {
    int idx = it * 256 + tid;
    int d = idx >> 3, scc = idx & 7;
    bf16x8 o;
    #pragma unroll
    for (int j = 0; j < 8; ++j) o[j] = *(const short*)&tile[scc * 8 + j][d];
    *(bf16x8*)(Vt + dstbase + (size_t)d * Sc + scc * 8) = o;
  }
}

// ---------------- causal GQA flash attention ----------------
// QBLK=128, 8 waves, T2 swizzle, heavy-first, T5, T13 +
// T14 async-STAGE: reg-load K/V(t+1) before compute(t), ds_write after barrier.
__global__ __launch_bounds__(512, 4) void flash_kernel(const bf16* __restrict__ Qn,
                                                       const bf16* __restrict__ Kn,
                                                       const bf16* __restrict__ Vt,
                                                       bf16* __restrict__ Out) {
  const int qi = 15 - (blockIdx.x >> 6);
  const int bh = blockIdx.x & 63;
  const int q0 = qi * 128;
  const int b = bh >> 4, h = bh & 15;
  const int kv = h >> 1;
  const int tid = threadIdx.x;
  const int wave = tid >> 6, lane = tid & 63;
  const int lg = lane >> 4, lr = lane & 15;
  const int rm = lr & 7;

  __shared__ __align__(16) bf16 sK[64][128];   // XOR-swizzled (16B slot ^= row&7)
  __shared__ __align__(16) bf16 sV[128][64];   // [d][s_local], XOR-swizzled
  __shared__ __align__(16) bf16 sP[8][16][72];

  const int qrow = q0 + wave * 16;
  const bf16* qbase = Qn + ((size_t)(b * Hc + h) * Sc + qrow + lr) * Dc;
  bf16x8 qf[4];
  #pragma unroll
  for (int kk = 0; kk < 4; ++kk) qf[kk] = *(const bf16x8*)(qbase + kk * 32 + lg * 8);

  f32x4 oacc[8];
  #pragma unroll
  for (int i = 0; i < 8; ++i) oacc[i] = (f32x4){0.f, 0.f, 0.f, 0.f};
  float m_run[4], l_run[4];
  #pragma unroll
  for (int r = 0; r < 4; ++r) { m_run[r] = -3.0e38f; l_run[r] = 0.f; }

  const bf16* kb = Kn + ((size_t)(b * KVc + kv) * Sc) * Dc;
  const bf16* vb = Vt + ((size_t)(b * KVc + kv) * Dc) * Sc;

  // T14 staging geometry: fixed per thread; global reads linear, LDS writes swizzled
  const bf16* kp[2]; const bf16* vp[2];
  bf16* kwp[2]; bf16* vwp[2];
  #pragma unroll
  for (int i2 = 0; i2 < 2; ++i2) {
    int idx = i2 * 512 + tid;
    int r = idx >> 4, ps = idx & 15;
    kp[i2] = kb + (size_t)r * Dc + ps * 8;
    kwp[i2] = &sK[r][(ps ^ (r & 7)) * 8];
    int r2 = idx >> 3, ps2 = idx & 7;
    vp[i2] = vb + (size_t)r2 * Sc + ps2 * 8;
    vwp[i2] = &sV[r2][(ps2 ^ (r2 & 7)) * 8];
  }

  bf16x8 rk[2], rv[2];
  // prologue: stage tile 0
  #pragma unroll
  for (int i2 = 0; i2 < 2; ++i2) { rk[i2] = *(const bf16x8*)kp[i2]; rv[i2] = *(const bf16x8*)vp[i2]; }
  #pragma unroll
  for (int i2 = 0; i2 < 2; ++i2) { *(bf16x8*)kwp[i2] = rk[i2]; *(bf16x8*)vwp[i2] = rv[i2]; }
  __syncthreads();

  const int nt = 2 * qi + 2;
  for (int t = 0; t < nt; ++t) {
    const int k0 = t * 64;
    // T14 issue-early: next tile's loads ride under this tile's compute
    if (t + 1 < nt) {
      #pragma unroll
      for (int i2 = 0; i2 < 2; ++i2) {
        rk[i2] = *(const bf16x8*)(kp[i2] + (size_t)(k0 + 64) * Dc);
        rv[i2] = *(const bf16x8*)(vp[i2] + k0 + 64);
      }
    }

    float tt[4][4];
    __builtin_amdgcn_s_setprio(1);
    #pragma unroll
    for (int c = 0; c < 4; ++c) {
      f32x4 sacc = (f32x4){0.f, 0.f, 0.f, 0.f};
      #pragma unroll
      for (int kk = 0; kk < 4; ++kk) {
        bf16x8 kf = *(const bf16x8*)&sK[c * 16 + lr][((kk * 4 + lg) ^ rm) * 8];
        sacc = MFMA16(qf[kk], kf, sacc);
      }
      if (k0 + c * 16 + 15 <= qrow) {  // wave-uniform: fully unmasked quadrant
        #pragma unroll
        for (int r = 0; r < 4; ++r) tt[c][r] = sacc[r];
      } else {
        int kg = k0 + c * 16 + lr;
        #pragma unroll
        for (int r = 0; r < 4; ++r) {
          int qg = qrow + lg * 4 + r;
          tt[c][r] = (kg <= qg) ? sacc[r] : -3.0e38f;
        }
      }
    }
    __builtin_amdgcn_s_setprio(0);

    float pmax[4];
    #pragma unroll
    for (int r = 0; r < 4; ++r) {
      float mx = fmaxf(fmaxf(tt[0][r], tt[1][r]), fmaxf(tt[2][r], tt[3][r]));
      mx = fmaxf(mx, __shfl_xor(mx, 1));
      mx = fmaxf(mx, __shfl_xor(mx, 2));
      mx = fmaxf(mx, __shfl_xor(mx, 4));
      mx = fmaxf(mx, __shfl_xor(mx, 8));
      pmax[r] = mx;
    }
    bool grow = (pmax[0] > m_run[0] + 8.f) || (pmax[1] > m_run[1] + 8.f) ||
                (pmax[2] > m_run[2] + 8.f) || (pmax[3] > m_run[3] + 8.f);
    if (__any(grow)) {
      #pragma unroll
      for (int r = 0; r < 4; ++r) {
        float mnew = fmaxf(m_run[r], pmax[r]);
        float alpha = exp2f(m_run[r] - mnew);
        m_run[r] = mnew;
        l_run[r] *= alpha;
        #pragma unroll
        for (int dc = 0; dc < 8; ++dc) oacc[dc][r] *= alpha;
      }
    }
    #pragma unroll
    for (int r = 0; r < 4; ++r) {
      float local = 0.f;
      #pragma unroll
      for (int c = 0; c < 4; ++c) { tt[c][r] = exp2f(tt[c][r] - m_run[r]); local += tt[c][r]; }
      l_run[r] += local;
    }
    #pragma unroll
    for (int c = 0; c < 4; ++c)
      #pragma unroll
      for (int r = 0; r < 4; ++r)
        sP[wave][lg * 4 + r][c * 16 + lr] = __float2bfloat16(tt[c][r]);

    __builtin_amdgcn_s_setprio(1);
    #pragma unroll
    for (int kk2 = 0; kk2 < 2; ++kk2) {
      bf16x8 pf = *(const bf16x8*)&sP[wave][lr][kk2 * 32 + lg * 8];
      #pragma unroll
      for (int dc = 0; dc < 8; ++dc) {
        bf16x8 vf = *(const bf16x8*)&sV[dc * 16 + lr][((kk2 * 4 + lg) ^ rm) * 8];
        oacc[dc] = MFMA16(pf, vf, oacc[dc]);
      }
    }
    __builtin_amdgcn_s_setprio(0);

    __syncthreads();  // (A) readers done with sK/sV; in-flight loads drained (cheap: compute covered them)
    if (t + 1 < nt) {
      #pragma unroll
      for (int i2 = 0; i2 < 2; ++i2) { *(bf16x8*)kwp[i2] = rk[i2]; *(bf16x8*)vwp[i2] = rv[i2]; }
    }
    __syncthreads();  // (B) writes visible to all waves
  }

  #pragma unroll
  for (int r = 0; r < 4; ++r) {
    float l = l_run[r];
    l += __shfl_xor(l, 1);
    l += __shfl_xor(l, 2);
    l += __shfl_xor(l, 4);
    l += __shfl_xor(l, 8);
    l_run[r] = 1.f / l;
  }
  #pragma unroll
  for (int dc = 0; dc < 8; ++dc)
    #pragma unroll
    for (int r = 0; r < 4; ++r) {
      size_t row = (size_t)b * Sc + qrow + lg * 4 + r;
      Out[row * (size_t)(Hc * Dc) + h * Dc + dc * 16 + lr] =
          __float2bfloat16(oacc[dc][r] * l_run[r]);
    }
}

// ---------------- launch ----------------
extern "C" void kernel_launch(void* const* d_in, const int* in_sizes, int n_in,
                              void* d_out, int out_size, void* d_ws, size_t ws_size,
                              hipStream_t stream) {
  const float* x    = (const float*)d_in[0];
  const float* cosT = (const float*)d_in[1];
  const float* sinT = (const float*)d_in[2];
  const float* wq   = (const float*)d_in[3];
  const float* wk   = (const float*)d_in[4];
  const float* wv   = (const float*)d_in[5];
  const float* wo   = (const float*)d_in[6];
  const float* qnw  = (const float*)d_in[7];
  const float* knw  = (const float*)d_in[8];
  float* out = (float*)d_out;

  const size_t MB = 1ull << 20;
  char* ws = (char*)d_ws;
  bf16* xb   = (bf16*)(ws + 0);        // 32MB  [8192][2048]
  bf16* wqkv = (bf16*)(ws + 32 * MB);  // 16MB  [4096][2048]
  bf16* wob  = (bf16*)(ws + 48 * MB);  // 8MB   [2048][2048]
  bf16* qkv  = (bf16*)(ws + 56 * MB);  // 64MB  [8192][4096]
  bf16* Qn   = (bf16*)(ws + 120 * MB); // 32MB  [B][H][S][D]
  bf16* Kn   = (bf16*)(ws + 152 * MB); // 16MB  [B][KV][S][D]
  bf16* Vt   = (bf16*)(ws + 168 * MB); // 16MB  [B][KV][D][S]
  bf16* attn = (bf16*)(ws + 184 * MB); // 32MB  [8192][2048]

  cvt_all<<<2048, 256, 0, stream>>>(x, wq, wk, wv, wo,
                                    (unsigned short*)xb, (unsigned short*)wqkv,
                                    (unsigned short*)wob);

  gemm8<bf16><<<512, 512, 0, stream>>>(xb, wqkv, qkv, 8192, 4096, 2048, 32, 16, 16, 4);
  norm_rope<<<8192, 256, 0, stream>>>(qkv, cosT, sinT, qnw, knw, Qn, Kn);
  v_transpose<<<dim3(32, 32), 256, 0, stream>>>(qkv, Vt);
  flash_kernel<<<1024, 512, 0, stream>>>(Qn, Kn, Vt, attn);
  gemm8<float><<<256, 512, 0, stream>>>(attn, wob, out, 8192, 2048, 2048, 32, 8, 8, 4);
}

// Round 8
// 385.894 us; speedup vs baseline: 1.0630x; 1.0630x over previous
//
#include <hip/hip_runtime.h>
#include <hip/hip_bf16.h>
#include <stdint.h>

using bf16 = __hip_bfloat16;
typedef __attribute__((ext_vector_type(8))) short bf16x8;
typedef __attribute__((ext_vector_type(4))) float f32x4;
typedef __attribute__((ext_vector_type(8))) unsigned short ushort8;

#define MFMA16(a,b,c) __builtin_amdgcn_mfma_f32_16x16x32_bf16(a,b,c,0,0,0)

static constexpr int Bc = 4, Sc = 2048, HSc = 2048, Hc = 16, KVc = 8, Dc = 128;

__device__ __forceinline__ void gl_lds16(const void* g, void* l) {
  __builtin_amdgcn_global_load_lds((const __attribute__((address_space(1))) uint32_t*)g,
                                   (__attribute__((address_space(3))) uint32_t*)l, 16, 0, 0);
}

__device__ __forceinline__ unsigned short f2bf(float f) {
  bf16 h = __float2bfloat16(f);
  return *reinterpret_cast<unsigned short*>(&h);
}

// ---------------- fused fp32 -> bf16 convert ----------------
__global__ __launch_bounds__(256) void cvt_all(const float* __restrict__ x,
                                               const float* __restrict__ wq,
                                               const float* __restrict__ wk,
                                               const float* __restrict__ wv,
                                               const float* __restrict__ wo,
                                               unsigned short* __restrict__ xb,
                                               unsigned short* __restrict__ wqkv,
                                               unsigned short* __restrict__ wob) {
  const int NX = 2097152, NQ = 524288, NK = 262144, NV = 262144, NO = 524288;
  const int T = NX + NQ + NK + NV + NO;
  int stride = gridDim.x * blockDim.x;
  for (int i = blockIdx.x * blockDim.x + threadIdx.x; i < T; i += stride) {
    const float* s;
    unsigned short* d;
    int j = i;
    if (j < NX) { s = x; d = xb; }
    else if ((j -= NX) < NQ) { s = wq; d = wqkv; }
    else if ((j -= NQ) < NK) { s = wk; d = wqkv + (size_t)NQ * 8; }
    else if ((j -= NK) < NV) { s = wv; d = wqkv + (size_t)(NQ + NK) * 8; }
    else { j -= NV; s = wo; d = wob; }
    const float4 a = *(const float4*)(s + (size_t)j * 8);
    const float4 b = *(const float4*)(s + (size_t)j * 8 + 4);
    ushort8 o;
    o[0] = f2bf(a.x); o[1] = f2bf(a.y); o[2] = f2bf(a.z); o[3] = f2bf(a.w);
    o[4] = f2bf(b.x); o[5] = f2bf(b.y); o[6] = f2bf(b.z); o[7] = f2bf(b.w);
    *(ushort8*)(d + (size_t)j * 8) = o;
  }
}

__device__ __forceinline__ void storeC(float* C, size_t i, float v) { C[i] = v; }
__device__ __forceinline__ void storeC(bf16* C, size_t i, float v) { C[i] = __float2bfloat16(v); }

// ---------------- 256x256 8-phase GEMM (unchanged) ----------------
#define LDA_(MI, BUF)                                                          \
  _Pragma("unroll") for (int rf = 0; rf < 4; ++rf)                             \
  _Pragma("unroll") for (int k = 0; k < 2; ++k) {                              \
    const int row_ = (MI * 4 + rf) * 16 + lr;                                  \
    a[rf][k] = *(const bf16x8*)&sA[BUF][wm][row_][((k * 4 + lg) ^ (row_ & 7)) * 8]; \
  }
#define LDB_(NI, BUF, BREG)                                                    \
  _Pragma("unroll") for (int j = 0; j < 2; ++j)                                \
  _Pragma("unroll") for (int k = 0; k < 2; ++k) {                              \
    const int row_ = (bco + NI * 2 + j) * 16 + lr;                             \
    BREG[j][k] = *(const bf16x8*)&sB[BUF][bh][row_][((k * 4 + lg) ^ (row_ & 7)) * 8]; \
  }
#define MM_(MI, NI, BREG)                                                      \
  __builtin_amdgcn_s_setprio(1);                                               \
  _Pragma("unroll") for (int rf = 0; rf < 4; ++rf)                             \
  _Pragma("unroll") for (int j = 0; j < 2; ++j)                                \
  _Pragma("unroll") for (int k = 0; k < 2; ++k)                                \
    acc[MI * 4 + rf][NI * 2 + j] =                                             \
        MFMA16(a[rf][k], BREG[j][k], acc[MI * 4 + rf][NI * 2 + j]);            \
  __builtin_amdgcn_s_setprio(0);
#define BAR_ __builtin_amdgcn_s_barrier();
#define VM4_ asm volatile("s_waitcnt vmcnt(4)" ::: "memory");
#define VM0_ asm volatile("s_waitcnt vmcnt(0)" ::: "memory");

template <typename OUT_T>
__global__ __launch_bounds__(512, 2) void gemm8(const bf16* __restrict__ A,
                                                const bf16* __restrict__ B,
                                                OUT_T* __restrict__ C,
                                                int M, int N, int K,
                                                int gm, int gn, int rbm, int rbn) {
  const int nwg = gridDim.x;
  const int cpx = nwg >> 3;
  const int swz = (blockIdx.x & 7) * cpx + (blockIdx.x >> 3);
  const int rsz = rbm * rbn;
  const int region = swz / rsz, rid = swz % rsz;
  const int regions_n = gn / rbn;
  const int bm = (region / regions_n) * rbm + rid / rbn;
  const int bn = (region % regions_n) * rbn + rid % rbn;

  __shared__ __align__(16) bf16 sA[2][2][128][64];
  __shared__ __align__(16) bf16 sB[2][2][128][64];

  const int tid = threadIdx.x;
  const int lane = tid & 63;
  const int wave = tid >> 6;
  const int wm = wave >> 2;
  const int wn = wave & 3;
  const int lg = lane >> 4, lr = lane & 15;
  const int bh = wn >> 1;
  const int bco = (wn & 1) * 4;

  const int rowA = bm * 256;
  const int colB = bn * 256;
  const int NT = K >> 6;

  f32x4 acc[8][4];
  #pragma unroll
  for (int i = 0; i < 8; ++i)
    #pragma unroll
    for (int j = 0; j < 4; ++j) acc[i][j] = (f32x4){0.f, 0.f, 0.f, 0.f};

  auto stA = [&](int buf, int half, int kt) {
    const bf16* src = A + (size_t)(rowA + half * 128) * K + kt * 64;
    #pragma unroll
    for (int is = 0; is < 2; ++is) {
      int r = is * 64 + (tid >> 3);
      int sl = (tid & 7) ^ (r & 7);
      gl_lds16(src + (size_t)r * K + sl * 8, &sA[buf][half][r][(tid & 7) * 8]);
    }
  };
  auto stB = [&](int buf, int half, int kt) {
    const bf16* src = B + (size_t)(colB + half * 128) * K + kt * 64;
    #pragma unroll
    for (int is = 0; is < 2; ++is) {
      int r = is * 64 + (tid >> 3);
      int sl = (tid & 7) ^ (r & 7);
      gl_lds16(src + (size_t)r * K + sl * 8, &sB[buf][half][r][(tid & 7) * 8]);
    }
  };

  stB(0, 0, 0); stB(0, 1, 0); stA(0, 0, 0); stA(0, 1, 0);
  stB(1, 0, 1); stB(1, 1, 1);
  VM4_
  __builtin_amdgcn_s_barrier();

  for (int t = 0; t < NT; t += 2) {
    const bool lastit = (t + 2 >= NT);
    bf16x8 a[4][2], bl[2][2], br[2][2];
    // ---------- K-tile t (buf0) ----------
    LDA_(0, 0) LDB_(0, 0, bl)
    stA(1, 0, t + 1);
    BAR_ MM_(0, 0, bl) BAR_
    LDB_(1, 0, br)
    stA(1, 1, t + 1);
    BAR_ MM_(0, 1, br) BAR_
    LDA_(1, 0)
    if (!lastit) stB(0, 0, t + 2);
    BAR_ MM_(1, 0, bl) BAR_
    if (!lastit) stB(0, 1, t + 2);
    BAR_ MM_(1, 1, br)
    if (lastit) { VM0_ } else { VM4_ }
    BAR_
    // ---------- K-tile t+1 (buf1) ----------
    LDA_(0, 1) LDB_(0, 1, bl)
    if (!lastit) stA(0, 0, t + 2);
    BAR_ MM_(0, 0, bl) BAR_
    LDB_(1, 1, br)
    if (!lastit) stA(0, 1, t + 2);
    BAR_ MM_(0, 1, br) BAR_
    LDA_(1, 1)
    if (t + 3 < NT) stB(1, 0, t + 3);
    BAR_ MM_(1, 0, bl) BAR_
    if (t + 3 < NT) stB(1, 1, t + 3);
    BAR_ MM_(1, 1, br)
    if (!lastit) { VM4_ }
    BAR_
  }

  #pragma unroll
  for (int rf = 0; rf < 8; ++rf)
    #pragma unroll
    for (int cf = 0; cf < 4; ++cf)
      #pragma unroll
      for (int r = 0; r < 4; ++r) {
        size_t row = rowA + wm * 128 + rf * 16 + lg * 4 + r;
        size_t col = colB + wn * 64 + cf * 16 + lr;
        storeC(C, row * (size_t)N + col, acc[rf][cf][r]);
      }
}

// ---------------- RMSNorm + RoPE on Q and K (Q pre-scaled by 1/sqrt(D)*log2e) ----------------
__global__ __launch_bounds__(256) void norm_rope(const bf16* __restrict__ qkv,
                                                 const float* __restrict__ cosT,
                                                 const float* __restrict__ sinT,
                                                 const float* __restrict__ qw,
                                                 const float* __restrict__ kw,
                                                 bf16* __restrict__ Qn, bf16* __restrict__ Kn) {
  const int bs = blockIdx.x;
  const int s = bs & (Sc - 1);
  const int b = bs >> 11;
  const int wave = threadIdx.x >> 6, lane = threadIdx.x & 63;
  const float QSCL = 0.08838834764831845f * 1.4426950408889634f;
  const float c0 = cosT[(size_t)s * Dc + lane];
  const float c1 = cosT[(size_t)s * Dc + 64 + lane];
  const float s0 = sinT[(size_t)s * Dc + lane];
  const float s1 = sinT[(size_t)s * Dc + 64 + lane];
  const bf16* row = qkv + (size_t)bs * 4096;
  #pragma unroll
  for (int i = 0; i < 6; ++i) {
    int head = wave * 6 + i;
    bool isQ = head < 16;
    int col = head * Dc;
    float x0 = __bfloat162float(row[col + lane]);
    float x1 = __bfloat162float(row[col + 64 + lane]);
    float ss = x0 * x0 + x1 * x1;
    #pragma unroll
    for (int off = 32; off; off >>= 1) ss += __shfl_xor(ss, off);
    float inv = rsqrtf(ss * (1.0f / 128.0f) + 1e-6f);
    const float* w = isQ ? qw : kw;
    float n0 = x0 * inv * w[lane];
    float n1 = x1 * inv * w[lane + 64];
    float o0 = n0 * c0 - n1 * s0;
    float o1 = n1 * c1 + n0 * s1;
    if (isQ) { o0 *= QSCL; o1 *= QSCL; }
    size_t base;
    bf16* dst;
    if (isQ) { base = ((size_t)(b * Hc + head) * Sc + s) * Dc; dst = Qn; }
    else     { base = ((size_t)(b * KVc + (head - 16)) * Sc + s) * Dc; dst = Kn; }
    dst[base + lane] = __float2bfloat16(o0);
    dst[base + 64 + lane] = __float2bfloat16(o1);
  }
}

// ---------------- V transpose: qkv V slice -> Vt [B][KV][D][S] ----------------
__global__ __launch_bounds__(256) void v_transpose(const bf16* __restrict__ qkv,
                                                   bf16* __restrict__ Vt) {
  const int s0 = blockIdx.x * 64;
  const int bk = blockIdx.y;
  __shared__ __align__(16) bf16 tile[64][136];
  const int tid = threadIdx.x;
  const size_t srcbase = ((size_t)(bk >> 3) * Sc + s0) * 4096 + 3072 + (size_t)(bk & 7) * Dc;
  #pragma unroll
  for (int it = 0; it < 4; ++it) {
    int idx = it * 256 + tid;
    int r = idx >> 4, ch = idx & 15;
    *(bf16x8*)&tile[r][ch * 8] = *(const bf16x8*)(qkv + srcbase + (size_t)r * 4096 + ch * 8);
  }
  __syncthreads();
  const size_t dstbase = (size_t)bk * Dc * Sc + s0;
  #pragma unroll
  for (int it = 0; it < 4; ++it) {
    int idx = it * 256 + tid;
    int d = idx >> 3, scc = idx & 7;
    bf16x8 o;
    #pragma unroll
    for (int j = 0; j < 8; ++j) o[j] = *(const short*)&tile[scc * 8 + j][d];
    *(bf16x8*)(Vt + dstbase + (size_t)d * Sc + scc * 8) = o;
  }
}

// ---------------- causal GQA flash attention ----------------
// ROUND-6 structure (gl_lds staging, proven 148us) + micro-opts:
// Q pre-scaled upstream, wave-uniform causal fast-path, T13 defer-max, T5 setprio.
// T14 reg-staging reverted (round-7: -10us regression, catalog-consistent).
__global__ __launch_bounds__(512, 4) void flash_kernel(const bf16* __restrict__ Qn,
                                                       const bf16* __restrict__ Kn,
                                                       const bf16* __restrict__ Vt,
                                                       bf16* __restrict__ Out) {
  const int qi = 15 - (blockIdx.x >> 6);
  const int bh = blockIdx.x & 63;
  const int q0 = qi * 128;
  const int b = bh >> 4, h = bh & 15;
  const int kv = h >> 1;
  const int tid = threadIdx.x;
  const int wave = tid >> 6, lane = tid & 63;
  const int lg = lane >> 4, lr = lane & 15;
  const int rm = lr & 7;

  __shared__ __align__(16) bf16 sK[64][128];   // XOR-swizzled (16B slot ^= row&7)
  __shared__ __align__(16) bf16 sV[128][64];   // [d][s_local], XOR-swizzled
  __shared__ __align__(16) bf16 sP[8][16][72];

  const int qrow = q0 + wave * 16;
  const bf16* qbase = Qn + ((size_t)(b * Hc + h) * Sc + qrow + lr) * Dc;
  bf16x8 qf[4];
  #pragma unroll
  for (int kk = 0; kk < 4; ++kk) qf[kk] = *(const bf16x8*)(qbase + kk * 32 + lg * 8);

  f32x4 oacc[8];
  #pragma unroll
  for (int i = 0; i < 8; ++i) oacc[i] = (f32x4){0.f, 0.f, 0.f, 0.f};
  float m_run[4], l_run[4];
  #pragma unroll
  for (int r = 0; r < 4; ++r) { m_run[r] = -3.0e38f; l_run[r] = 0.f; }

  const bf16* kb = Kn + ((size_t)(b * KVc + kv) * Sc) * Dc;
  const bf16* vb = Vt + ((size_t)(b * KVc + kv) * Dc) * Sc;

  const int nt = 2 * qi + 2;
  for (int t = 0; t < nt; ++t) {
    const int k0 = t * 64;
    #pragma unroll
    for (int it = 0; it < 2; ++it) {
      int idx = it * 512 + tid;
      int r = idx >> 4, ps = idx & 15;
      int ls = ps ^ (r & 7);
      gl_lds16(kb + (size_t)(k0 + r) * Dc + ls * 8, &sK[r][ps * 8]);
    }
    #pragma unroll
    for (int it = 0; it < 2; ++it) {
      int idx = it * 512 + tid;
      int r = idx >> 3, ps = idx & 7;
      int ls = ps ^ (r & 7);
      gl_lds16(vb + (size_t)r * Sc + k0 + ls * 8, &sV[r][ps * 8]);
    }
    __syncthreads();  // vmcnt(0) drain + barrier: tile staged

    float tt[4][4];
    __builtin_amdgcn_s_setprio(1);
    #pragma unroll
    for (int c = 0; c < 4; ++c) {
      f32x4 sacc = (f32x4){0.f, 0.f, 0.f, 0.f};
      #pragma unroll
      for (int kk = 0; kk < 4; ++kk) {
        bf16x8 kf = *(const bf16x8*)&sK[c * 16 + lr][((kk * 4 + lg) ^ rm) * 8];
        sacc = MFMA16(qf[kk], kf, sacc);
      }
      if (k0 + c * 16 + 15 <= qrow) {  // wave-uniform: fully unmasked quadrant
        #pragma unroll
        for (int r = 0; r < 4; ++r) tt[c][r] = sacc[r];
      } else {
        int kg = k0 + c * 16 + lr;
        #pragma unroll
        for (int r = 0; r < 4; ++r) {
          int qg = qrow + lg * 4 + r;
          tt[c][r] = (kg <= qg) ? sacc[r] : -3.0e38f;
        }
      }
    }
    __builtin_amdgcn_s_setprio(0);

    float pmax[4];
    #pragma unroll
    for (int r = 0; r < 4; ++r) {
      float mx = fmaxf(fmaxf(tt[0][r], tt[1][r]), fmaxf(tt[2][r], tt[3][r]));
      mx = fmaxf(mx, __shfl_xor(mx, 1));
      mx = fmaxf(mx, __shfl_xor(mx, 2));
      mx = fmaxf(mx, __shfl_xor(mx, 4));
      mx = fmaxf(mx, __shfl_xor(mx, 8));
      pmax[r] = mx;
    }
    bool grow = (pmax[0] > m_run[0] + 8.f) || (pmax[1] > m_run[1] + 8.f) ||
                (pmax[2] > m_run[2] + 8.f) || (pmax[3] > m_run[3] + 8.f);
    if (__any(grow)) {
      #pragma unroll
      for (int r = 0; r < 4; ++r) {
        float mnew = fmaxf(m_run[r], pmax[r]);
        float alpha = exp2f(m_run[r] - mnew);
        m_run[r] = mnew;
        l_run[r] *= alpha;
        #pragma unroll
        for (int dc = 0; dc < 8; ++dc) oacc[dc][r] *= alpha;
      }
    }
    #pragma unroll
    for (int r = 0; r < 4; ++r) {
      float local = 0.f;
      #pragma unroll
      for (int c = 0; c < 4; ++c) { tt[c][r] = exp2f(tt[c][r] - m_run[r]); local += tt[c][r]; }
      l_run[r] += local;
    }
    #pragma unroll
    for (int c = 0; c < 4; ++c)
      #pragma unroll
      for (int r = 0; r < 4; ++r)
        sP[wave][lg * 4 + r][c * 16 + lr] = __float2bfloat16(tt[c][r]);

    __builtin_amdgcn_s_setprio(1);
    #pragma unroll
    for (int kk2 = 0; kk2 < 2; ++kk2) {
      bf16x8 pf = *(const bf16x8*)&sP[wave][lr][kk2 * 32 + lg * 8];
      #pragma unroll
      for (int dc = 0; dc < 8; ++dc) {
        bf16x8 vf = *(const bf16x8*)&sV[dc * 16 + lr][((kk2 * 4 + lg) ^ rm) * 8];
        oacc[dc] = MFMA16(pf, vf, oacc[dc]);
      }
    }
    __builtin_amdgcn_s_setprio(0);

    __syncthreads();  // all waves done with sK/sV before next tile overwrites
  }

  #pragma unroll
  for (int r = 0; r < 4; ++r) {
    float l = l_run[r];
    l += __shfl_xor(l, 1);
    l += __shfl_xor(l, 2);
    l += __shfl_xor(l, 4);
    l += __shfl_xor(l, 8);
    l_run[r] = 1.f / l;
  }
  #pragma unroll
  for (int dc = 0; dc < 8; ++dc)
    #pragma unroll
    for (int r = 0; r < 4; ++r) {
      size_t row = (size_t)b * Sc + qrow + lg * 4 + r;
      Out[row * (size_t)(Hc * Dc) + h * Dc + dc * 16 + lr] =
          __float2bfloat16(oacc[dc][r] * l_run[r]);
    }
}

// ---------------- launch ----------------
extern "C" void kernel_launch(void* const* d_in, const int* in_sizes, int n_in,
                              void* d_out, int out_size, void* d_ws, size_t ws_size,
                              hipStream_t stream) {
  const float* x    = (const float*)d_in[0];
  const float* cosT = (const float*)d_in[1];
  const float* sinT = (const float*)d_in[2];
  const float* wq   = (const float*)d_in[3];
  const float* wk   = (const float*)d_in[4];
  const float* wv   = (const float*)d_in[5];
  const float* wo   = (const float*)d_in[6];
  const float* qnw  = (const float*)d_in[7];
  const float* knw  = (const float*)d_in[8];
  float* out = (float*)d_out;

  const size_t MB = 1ull << 20;
  char* ws = (char*)d_ws;
  bf16* xb   = (bf16*)(ws + 0);        // 32MB  [8192][2048]
  bf16* wqkv = (bf16*)(ws + 32 * MB);  // 16MB  [4096][2048]
  bf16* wob  = (bf16*)(ws + 48 * MB);  // 8MB   [2048][2048]
  bf16* qkv  = (bf16*)(ws + 56 * MB);  // 64MB  [8192][4096]
  bf16* Qn   = (bf16*)(ws + 120 * MB); // 32MB  [B][H][S][D]
  bf16* Kn   = (bf16*)(ws + 152 * MB); // 16MB  [B][KV][S][D]
  bf16* Vt   = (bf16*)(ws + 168 * MB); // 16MB  [B][KV][D][S]
  bf16* attn = (bf16*)(ws + 184 * MB); // 32MB  [8192][2048]

  cvt_all<<<2048, 256, 0, stream>>>(x, wq, wk, wv, wo,
                                    (unsigned short*)xb, (unsigned short*)wqkv,
                                    (unsigned short*)wob);

  gemm8<bf16><<<512, 512, 0, stream>>>(xb, wqkv, qkv, 8192, 4096, 2048, 32, 16, 16, 4);
  norm_rope<<<8192, 256, 0, stream>>>(qkv, cosT, sinT, qnw, knw, Qn, Kn);
  v_transpose<<<dim3(32, 32), 256, 0, stream>>>(qkv, Vt);
  flash_kernel<<<1024, 512, 0, stream>>>(Qn, Kn, Vt, attn);
  gemm8<float><<<256, 512, 0, stream>>>(attn, wob, out, 8192, 2048, 2048, 32, 8, 8, 4);
}

// Round 9
// 384.650 us; speedup vs baseline: 1.0664x; 1.0032x over previous
//
#include <hip/hip_runtime.h>
#include <hip/hip_bf16.h>
#include <stdint.h>

using bf16 = __hip_bfloat16;
typedef __attribute__((ext_vector_type(8))) short bf16x8;
typedef __attribute__((ext_vector_type(4))) float f32x4;
typedef __attribute__((ext_vector_type(8))) unsigned short ushort8;

#define MFMA16(a,b,c) __builtin_amdgcn_mfma_f32_16x16x32_bf16(a,b,c,0,0,0)

static constexpr int Bc = 4, Sc = 2048, HSc = 2048, Hc = 16, KVc = 8, Dc = 128;

__device__ __forceinline__ void gl_lds16(const void* g, void* l) {
  __builtin_amdgcn_global_load_lds((const __attribute__((address_space(1))) uint32_t*)g,
                                   (__attribute__((address_space(3))) uint32_t*)l, 16, 0, 0);
}

__device__ __forceinline__ unsigned short f2bf(float f) {
  bf16 h = __float2bfloat16(f);
  return *reinterpret_cast<unsigned short*>(&h);
}

// ---------------- fused fp32 -> bf16 convert ----------------
__global__ __launch_bounds__(256) void cvt_all(const float* __restrict__ x,
                                               const float* __restrict__ wq,
                                               const float* __restrict__ wk,
                                               const float* __restrict__ wv,
                                               const float* __restrict__ wo,
                                               unsigned short* __restrict__ xb,
                                               unsigned short* __restrict__ wqkv,
                                               unsigned short* __restrict__ wob) {
  const int NX = 2097152, NQ = 524288, NK = 262144, NV = 262144, NO = 524288;
  const int T = NX + NQ + NK + NV + NO;
  int stride = gridDim.x * blockDim.x;
  for (int i = blockIdx.x * blockDim.x + threadIdx.x; i < T; i += stride) {
    const float* s;
    unsigned short* d;
    int j = i;
    if (j < NX) { s = x; d = xb; }
    else if ((j -= NX) < NQ) { s = wq; d = wqkv; }
    else if ((j -= NQ) < NK) { s = wk; d = wqkv + (size_t)NQ * 8; }
    else if ((j -= NK) < NV) { s = wv; d = wqkv + (size_t)(NQ + NK) * 8; }
    else { j -= NV; s = wo; d = wob; }
    const float4 a = *(const float4*)(s + (size_t)j * 8);
    const float4 b = *(const float4*)(s + (size_t)j * 8 + 4);
    ushort8 o;
    o[0] = f2bf(a.x); o[1] = f2bf(a.y); o[2] = f2bf(a.z); o[3] = f2bf(a.w);
    o[4] = f2bf(b.x); o[5] = f2bf(b.y); o[6] = f2bf(b.z); o[7] = f2bf(b.w);
    *(ushort8*)(d + (size_t)j * 8) = o;
  }
}

__device__ __forceinline__ void storeC(float* C, size_t i, float v) { C[i] = v; }
__device__ __forceinline__ void storeC(bf16* C, size_t i, float v) { C[i] = __float2bfloat16(v); }

// ---------------- 256x256 8-phase GEMM (unchanged) ----------------
#define LDA_(MI, BUF)                                                          \
  _Pragma("unroll") for (int rf = 0; rf < 4; ++rf)                             \
  _Pragma("unroll") for (int k = 0; k < 2; ++k) {                              \
    const int row_ = (MI * 4 + rf) * 16 + lr;                                  \
    a[rf][k] = *(const bf16x8*)&sA[BUF][wm][row_][((k * 4 + lg) ^ (row_ & 7)) * 8]; \
  }
#define LDB_(NI, BUF, BREG)                                                    \
  _Pragma("unroll") for (int j = 0; j < 2; ++j)                                \
  _Pragma("unroll") for (int k = 0; k < 2; ++k) {                              \
    const int row_ = (bco + NI * 2 + j) * 16 + lr;                             \
    BREG[j][k] = *(const bf16x8*)&sB[BUF][bh][row_][((k * 4 + lg) ^ (row_ & 7)) * 8]; \
  }
#define MM_(MI, NI, BREG)                                                      \
  __builtin_amdgcn_s_setprio(1);                                               \
  _Pragma("unroll") for (int rf = 0; rf < 4; ++rf)                             \
  _Pragma("unroll") for (int j = 0; j < 2; ++j)                                \
  _Pragma("unroll") for (int k = 0; k < 2; ++k)                                \
    acc[MI * 4 + rf][NI * 2 + j] =                                             \
        MFMA16(a[rf][k], BREG[j][k], acc[MI * 4 + rf][NI * 2 + j]);            \
  __builtin_amdgcn_s_setprio(0);
#define BAR_ __builtin_amdgcn_s_barrier();
#define VM4_ asm volatile("s_waitcnt vmcnt(4)" ::: "memory");
#define VM0_ asm volatile("s_waitcnt vmcnt(0)" ::: "memory");

template <typename OUT_T>
__global__ __launch_bounds__(512, 2) void gemm8(const bf16* __restrict__ A,
                                                const bf16* __restrict__ B,
                                                OUT_T* __restrict__ C,
                                                int M, int N, int K,
                                                int gm, int gn, int rbm, int rbn) {
  const int nwg = gridDim.x;
  const int cpx = nwg >> 3;
  const int swz = (blockIdx.x & 7) * cpx + (blockIdx.x >> 3);
  const int rsz = rbm * rbn;
  const int region = swz / rsz, rid = swz % rsz;
  const int regions_n = gn / rbn;
  const int bm = (region / regions_n) * rbm + rid / rbn;
  const int bn = (region % regions_n) * rbn + rid % rbn;

  __shared__ __align__(16) bf16 sA[2][2][128][64];
  __shared__ __align__(16) bf16 sB[2][2][128][64];

  const int tid = threadIdx.x;
  const int lane = tid & 63;
  const int wave = tid >> 6;
  const int wm = wave >> 2;
  const int wn = wave & 3;
  const int lg = lane >> 4, lr = lane & 15;
  const int bh = wn >> 1;
  const int bco = (wn & 1) * 4;

  const int rowA = bm * 256;
  const int colB = bn * 256;
  const int NT = K >> 6;

  f32x4 acc[8][4];
  #pragma unroll
  for (int i = 0; i < 8; ++i)
    #pragma unroll
    for (int j = 0; j < 4; ++j) acc[i][j] = (f32x4){0.f, 0.f, 0.f, 0.f};

  auto stA = [&](int buf, int half, int kt) {
    const bf16* src = A + (size_t)(rowA + half * 128) * K + kt * 64;
    #pragma unroll
    for (int is = 0; is < 2; ++is) {
      int r = is * 64 + (tid >> 3);
      int sl = (tid & 7) ^ (r & 7);
      gl_lds16(src + (size_t)r * K + sl * 8, &sA[buf][half][r][(tid & 7) * 8]);
    }
  };
  auto stB = [&](int buf, int half, int kt) {
    const bf16* src = B + (size_t)(colB + half * 128) * K + kt * 64;
    #pragma unroll
    for (int is = 0; is < 2; ++is) {
      int r = is * 64 + (tid >> 3);
      int sl = (tid & 7) ^ (r & 7);
      gl_lds16(src + (size_t)r * K + sl * 8, &sB[buf][half][r][(tid & 7) * 8]);
    }
  };

  stB(0, 0, 0); stB(0, 1, 0); stA(0, 0, 0); stA(0, 1, 0);
  stB(1, 0, 1); stB(1, 1, 1);
  VM4_
  __builtin_amdgcn_s_barrier();

  for (int t = 0; t < NT; t += 2) {
    const bool lastit = (t + 2 >= NT);
    bf16x8 a[4][2], bl[2][2], br[2][2];
    // ---------- K-tile t (buf0) ----------
    LDA_(0, 0) LDB_(0, 0, bl)
    stA(1, 0, t + 1);
    BAR_ MM_(0, 0, bl) BAR_
    LDB_(1, 0, br)
    stA(1, 1, t + 1);
    BAR_ MM_(0, 1, br) BAR_
    LDA_(1, 0)
    if (!lastit) stB(0, 0, t + 2);
    BAR_ MM_(1, 0, bl) BAR_
    if (!lastit) stB(0, 1, t + 2);
    BAR_ MM_(1, 1, br)
    if (lastit) { VM0_ } else { VM4_ }
    BAR_
    // ---------- K-tile t+1 (buf1) ----------
    LDA_(0, 1) LDB_(0, 1, bl)
    if (!lastit) stA(0, 0, t + 2);
    BAR_ MM_(0, 0, bl) BAR_
    LDB_(1, 1, br)
    if (!lastit) stA(0, 1, t + 2);
    BAR_ MM_(0, 1, br) BAR_
    LDA_(1, 1)
    if (t + 3 < NT) stB(1, 0, t + 3);
    BAR_ MM_(1, 0, bl) BAR_
    if (t + 3 < NT) stB(1, 1, t + 3);
    BAR_ MM_(1, 1, br)
    if (!lastit) { VM4_ }
    BAR_
  }

  #pragma unroll
  for (int rf = 0; rf < 8; ++rf)
    #pragma unroll
    for (int cf = 0; cf < 4; ++cf)
      #pragma unroll
      for (int r = 0; r < 4; ++r) {
        size_t row = rowA + wm * 128 + rf * 16 + lg * 4 + r;
        size_t col = colB + wn * 64 + cf * 16 + lr;
        storeC(C, row * (size_t)N + col, acc[rf][cf][r]);
      }
}

// ---------------- RMSNorm + RoPE on Q and K (Q pre-scaled by 1/sqrt(D)*log2e) ----------------
__global__ __launch_bounds__(256) void norm_rope(const bf16* __restrict__ qkv,
                                                 const float* __restrict__ cosT,
                                                 const float* __restrict__ sinT,
                                                 const float* __restrict__ qw,
                                                 const float* __restrict__ kw,
                                                 bf16* __restrict__ Qn, bf16* __restrict__ Kn) {
  const int bs = blockIdx.x;
  const int s = bs & (Sc - 1);
  const int b = bs >> 11;
  const int wave = threadIdx.x >> 6, lane = threadIdx.x & 63;
  const float QSCL = 0.08838834764831845f * 1.4426950408889634f;
  const float c0 = cosT[(size_t)s * Dc + lane];
  const float c1 = cosT[(size_t)s * Dc + 64 + lane];
  const float s0 = sinT[(size_t)s * Dc + lane];
  const float s1 = sinT[(size_t)s * Dc + 64 + lane];
  const bf16* row = qkv + (size_t)bs * 4096;
  #pragma unroll
  for (int i = 0; i < 6; ++i) {
    int head = wave * 6 + i;
    bool isQ = head < 16;
    int col = head * Dc;
    float x0 = __bfloat162float(row[col + lane]);
    float x1 = __bfloat162float(row[col + 64 + lane]);
    float ss = x0 * x0 + x1 * x1;
    #pragma unroll
    for (int off = 32; off; off >>= 1) ss += __shfl_xor(ss, off);
    float inv = rsqrtf(ss * (1.0f / 128.0f) + 1e-6f);
    const float* w = isQ ? qw : kw;
    float n0 = x0 * inv * w[lane];
    float n1 = x1 * inv * w[lane + 64];
    float o0 = n0 * c0 - n1 * s0;
    float o1 = n1 * c1 + n0 * s1;
    if (isQ) { o0 *= QSCL; o1 *= QSCL; }
    size_t base;
    bf16* dst;
    if (isQ) { base = ((size_t)(b * Hc + head) * Sc + s) * Dc; dst = Qn; }
    else     { base = ((size_t)(b * KVc + (head - 16)) * Sc + s) * Dc; dst = Kn; }
    dst[base + lane] = __float2bfloat16(o0);
    dst[base + 64 + lane] = __float2bfloat16(o1);
  }
}

// ---------------- V transpose: qkv V slice -> Vt [B][KV][D][S] ----------------
__global__ __launch_bounds__(256) void v_transpose(const bf16* __restrict__ qkv,
                                                   bf16* __restrict__ Vt) {
  const int s0 = blockIdx.x * 64;
  const int bk = blockIdx.y;
  __shared__ __align__(16) bf16 tile[64][136];
  const int tid = threadIdx.x;
  const size_t srcbase = ((size_t)(bk >> 3) * Sc + s0) * 4096 + 3072 + (size_t)(bk & 7) * Dc;
  #pragma unroll
  for (int it = 0; it < 4; ++it) {
    int idx = it * 256 + tid;
    int r = idx >> 4, ch = idx & 15;
    *(bf16x8*)&tile[r][ch * 8] = *(const bf16x8*)(qkv + srcbase + (size_t)r * 4096 + ch * 8);
  }
  __syncthreads();
  const size_t dstbase = (size_t)bk * Dc * Sc + s0;
  #pragma unroll
  for (int it = 0; it < 4; ++it) {
    int idx = it * 256 + tid;
    int d = idx >> 3, scc = idx & 7;
    bf16x8 o;
    #pragma unroll
    for (int j = 0; j < 8; ++j) o[j] = *(const short*)&tile[scc * 8 + j][d];
    *(bf16x8*)(Vt + dstbase + (size_t)d * Sc + scc * 8) = o;
  }
}

// ---------------- causal GQA flash attention ----------------
// Round-6 staging structure + SWAPPED QK^T (S^T = mfma(K,Q)): lane owns ONE q-row
// -> in-lane softmax (15 fmax + 2 shfl) with per-lane scalar m/l; alpha reaches the
// PV-layout rows via 4 broadcast shfls in the rare rescale branch. sP writes are
// b32 r-pair packed + 16B-block XOR swizzle (kills the 16-bank pileup = 1e7 conflicts).
__global__ __launch_bounds__(512, 4) void flash_kernel(const bf16* __restrict__ Qn,
                                                       const bf16* __restrict__ Kn,
                                                       const bf16* __restrict__ Vt,
                                                       bf16* __restrict__ Out) {
  const int qi = 15 - (blockIdx.x >> 6);
  const int bh = blockIdx.x & 63;
  const int q0 = qi * 128;
  const int b = bh >> 4, h = bh & 15;
  const int kv = h >> 1;
  const int tid = threadIdx.x;
  const int wave = tid >> 6, lane = tid & 63;
  const int lg = lane >> 4, lr = lane & 15;
  const int rm = lr & 7;

  __shared__ __align__(16) bf16 sK[64][128];     // XOR-swizzled (16B slot ^= row&7)
  __shared__ __align__(16) bf16 sV[128][64];     // [d][s_local], XOR-swizzled
  __shared__ __align__(16) unsigned short sP[8][16][72];  // [wave][q=lr][k], XOR-swizzled blocks

  const int qrow = q0 + wave * 16;
  const bf16* qbase = Qn + ((size_t)(b * Hc + h) * Sc + qrow + lr) * Dc;
  bf16x8 qf[4];
  #pragma unroll
  for (int kk = 0; kk < 4; ++kk) qf[kk] = *(const bf16x8*)(qbase + kk * 32 + lg * 8);

  f32x4 oacc[8];
  #pragma unroll
  for (int i = 0; i < 8; ++i) oacc[i] = (f32x4){0.f, 0.f, 0.f, 0.f};
  float m_run = -3.0e38f, l_run = 0.f;   // per-lane scalars: this lane's q-row = qrow+lr

  const bf16* kb = Kn + ((size_t)(b * KVc + kv) * Sc) * Dc;
  const bf16* vb = Vt + ((size_t)(b * KVc + kv) * Dc) * Sc;

  const int nt = 2 * qi + 2;
  for (int t = 0; t < nt; ++t) {
    const int k0 = t * 64;
    #pragma unroll
    for (int it = 0; it < 2; ++it) {
      int idx = it * 512 + tid;
      int r = idx >> 4, ps = idx & 15;
      int ls = ps ^ (r & 7);
      gl_lds16(kb + (size_t)(k0 + r) * Dc + ls * 8, &sK[r][ps * 8]);
    }
    #pragma unroll
    for (int it = 0; it < 2; ++it) {
      int idx = it * 512 + tid;
      int r = idx >> 3, ps = idx & 7;
      int ls = ps ^ (r & 7);
      gl_lds16(vb + (size_t)r * Sc + k0 + ls * 8, &sV[r][ps * 8]);
    }
    __syncthreads();  // vmcnt(0) drain + barrier: tile staged

    // QK^T swapped: tt[c][r] = S[q=qrow+lr][k = k0 + c*16 + lg*4 + r]
    float tt[4][4];
    const int qg = qrow + lr;
    __builtin_amdgcn_s_setprio(1);
    #pragma unroll
    for (int c = 0; c < 4; ++c) {
      f32x4 sacc = (f32x4){0.f, 0.f, 0.f, 0.f};
      #pragma unroll
      for (int kk = 0; kk < 4; ++kk) {
        bf16x8 kf = *(const bf16x8*)&sK[c * 16 + lr][((kk * 4 + lg) ^ rm) * 8];
        sacc = MFMA16(kf, qf[kk], sacc);   // A=K, B=Q -> D[k][q]
      }
      if (k0 + c * 16 + 15 <= qrow) {      // wave-uniform: fully unmasked quadrant
        #pragma unroll
        for (int r = 0; r < 4; ++r) tt[c][r] = sacc[r];
      } else {
        #pragma unroll
        for (int r = 0; r < 4; ++r) {
          int kg = k0 + c * 16 + lg * 4 + r;
          tt[c][r] = (kg <= qg) ? sacc[r] : -3.0e38f;
        }
      }
    }
    __builtin_amdgcn_s_setprio(0);

    // in-lane row max + 2 cross-half shfls (lanes lr, lr+16, lr+32, lr+48 share row)
    float m0 = fmaxf(fmaxf(tt[0][0], tt[0][1]), fmaxf(tt[0][2], tt[0][3]));
    float m1 = fmaxf(fmaxf(tt[1][0], tt[1][1]), fmaxf(tt[1][2], tt[1][3]));
    float m2 = fmaxf(fmaxf(tt[2][0], tt[2][1]), fmaxf(tt[2][2], tt[2][3]));
    float m3 = fmaxf(fmaxf(tt[3][0], tt[3][1]), fmaxf(tt[3][2], tt[3][3]));
    float mx = fmaxf(fmaxf(m0, m1), fmaxf(m2, m3));
    mx = fmaxf(mx, __shfl_xor(mx, 16));
    mx = fmaxf(mx, __shfl_xor(mx, 32));

    bool grow = mx > m_run + 8.f;   // T13 defer-max
    if (__any(grow)) {
      float mnew = fmaxf(m_run, mx);
      float alpha = exp2f(m_run - mnew);
      m_run = mnew;
      l_run *= alpha;
      // broadcast alpha to PV-layout rows (oacc row q = qrow + lg*4 + r lives at src lane lg*4+r)
      float a0 = __shfl(alpha, lg * 4 + 0);
      float a1 = __shfl(alpha, lg * 4 + 1);
      float a2 = __shfl(alpha, lg * 4 + 2);
      float a3 = __shfl(alpha, lg * 4 + 3);
      #pragma unroll
      for (int dc = 0; dc < 8; ++dc) {
        oacc[dc][0] *= a0; oacc[dc][1] *= a1; oacc[dc][2] *= a2; oacc[dc][3] *= a3;
      }
    }
    float lsum = 0.f;
    #pragma unroll
    for (int c = 0; c < 4; ++c)
      #pragma unroll
      for (int r = 0; r < 4; ++r) { tt[c][r] = exp2f(tt[c][r] - m_run); lsum += tt[c][r]; }
    l_run += lsum;  // per-lane partial; reduced across halves after the loop

    // P write: lane holds P[q=lr][k=c*16+lg*4+r] -> pack r-pairs (consecutive k) as b32,
    // 16B-block XOR swizzle (blk ^= lr&7) matching the b128 read below.
    #pragma unroll
    for (int c = 0; c < 4; ++c)
      #pragma unroll
      for (int r2 = 0; r2 < 2; ++r2) {
        int col = c * 16 + lg * 4 + 2 * r2;
        int colx = (((col >> 3) ^ rm) << 3) + (col & 7);
        ushort2 w;
        w.x = f2bf(tt[c][2 * r2]);
        w.y = f2bf(tt[c][2 * r2 + 1]);
        *(ushort2*)&sP[wave][lr][colx] = w;
      }

    __builtin_amdgcn_s_setprio(1);
    #pragma unroll
    for (int kk2 = 0; kk2 < 2; ++kk2) {
      bf16x8 pf = *(const bf16x8*)&sP[wave][lr][((kk2 * 4 + lg) ^ rm) * 8];
      #pragma unroll
      for (int dc = 0; dc < 8; ++dc) {
        bf16x8 vf = *(const bf16x8*)&sV[dc * 16 + lr][((kk2 * 4 + lg) ^ rm) * 8];
        oacc[dc] = MFMA16(pf, vf, oacc[dc]);
      }
    }
    __builtin_amdgcn_s_setprio(0);

    __syncthreads();  // all waves done with sK/sV before next tile overwrites
  }

  // row-l lives split across the 4 lanes of each row: reduce, invert, broadcast to PV rows
  float l = l_run;
  l += __shfl_xor(l, 16);
  l += __shfl_xor(l, 32);
  float linv = 1.f / l;
  float li0 = __shfl(linv, lg * 4 + 0);
  float li1 = __shfl(linv, lg * 4 + 1);
  float li2 = __shfl(linv, lg * 4 + 2);
  float li3 = __shfl(linv, lg * 4 + 3);
  #pragma unroll
  for (int dc = 0; dc < 8; ++dc) {
    size_t rowb = (size_t)b * Sc + qrow + lg * 4;
    size_t colb = (size_t)h * Dc + dc * 16 + lr;
    Out[(rowb + 0) * (size_t)(Hc * Dc) + colb] = __float2bfloat16(oacc[dc][0] * li0);
    Out[(rowb + 1) * (size_t)(Hc * Dc) + colb] = __float2bfloat16(oacc[dc][1] * li1);
    Out[(rowb + 2) * (size_t)(Hc * Dc) + colb] = __float2bfloat16(oacc[dc][2] * li2);
    Out[(rowb + 3) * (size_t)(Hc * Dc) + colb] = __float2bfloat16(oacc[dc][3] * li3);
  }
}

// ---------------- launch ----------------
extern "C" void kernel_launch(void* const* d_in, const int* in_sizes, int n_in,
                              void* d_out, int out_size, void* d_ws, size_t ws_size,
                              hipStream_t stream) {
  const float* x    = (const float*)d_in[0];
  const float* cosT = (const float*)d_in[1];
  const float* sinT = (const float*)d_in[2];
  const float* wq   = (const float*)d_in[3];
  const float* wk   = (const float*)d_in[4];
  const float* wv   = (const float*)d_in[5];
  const float* wo   = (const float*)d_in[6];
  const float* qnw  = (const float*)d_in[7];
  const float* knw  = (const float*)d_in[8];
  float* out = (float*)d_out;

  const size_t MB = 1ull << 20;
  char* ws = (char*)d_ws;
  bf16* xb   = (bf16*)(ws + 0);        // 32MB  [8192][2048]
  bf16* wqkv = (bf16*)(ws + 32 * MB);  // 16MB  [4096][2048]
  bf16* wob  = (bf16*)(ws + 48 * MB);  // 8MB   [2048][2048]
  bf16* qkv  = (bf16*)(ws + 56 * MB);  // 64MB  [8192][4096]
  bf16* Qn   = (bf16*)(ws + 120 * MB); // 32MB  [B][H][S][D]
  bf16* Kn   = (bf16*)(ws + 152 * MB); // 16MB  [B][KV][S][D]
  bf16* Vt   = (bf16*)(ws + 168 * MB); // 16MB  [B][KV][D][S]
  bf16* attn = (bf16*)(ws + 184 * MB); // 32MB  [8192][2048]

  cvt_all<<<2048, 256, 0, stream>>>(x, wq, wk, wv, wo,
                                    (unsigned short*)xb, (unsigned short*)wqkv,
                                    (unsigned short*)wob);

  gemm8<bf16><<<512, 512, 0, stream>>>(xb, wqkv, qkv, 8192, 4096, 2048, 32, 16, 16, 4);
  norm_rope<<<8192, 256, 0, stream>>>(qkv, cosT, sinT, qnw, knw, Qn, Kn);
  v_transpose<<<dim3(32, 32), 256, 0, stream>>>(qkv, Vt);
  flash_kernel<<<1024, 512, 0, stream>>>(Qn, Kn, Vt, attn);
  gemm8<float><<<256, 512, 0, stream>>>(attn, wob, out, 8192, 2048, 2048, 32, 8, 8, 4);
}

// Round 10
// 363.985 us; speedup vs baseline: 1.1270x; 1.0568x over previous
//
#include <hip/hip_runtime.h>
#include <hip/hip_bf16.h>
#include <stdint.h>

using bf16 = __hip_bfloat16;
typedef __attribute__((ext_vector_type(8))) short bf16x8;
typedef __attribute__((ext_vector_type(4))) float f32x4;
typedef __attribute__((ext_vector_type(8))) unsigned short ushort8;

#define MFMA16(a,b,c) __builtin_amdgcn_mfma_f32_16x16x32_bf16(a,b,c,0,0,0)

static constexpr int Bc = 4, Sc = 2048, HSc = 2048, Hc = 16, KVc = 8, Dc = 128;

__device__ __forceinline__ void gl_lds16(const void* g, void* l) {
  __builtin_amdgcn_global_load_lds((const __attribute__((address_space(1))) uint32_t*)g,
                                   (__attribute__((address_space(3))) uint32_t*)l, 16, 0, 0);
}

__device__ __forceinline__ unsigned short f2bf(float f) {
  bf16 h = __float2bfloat16(f);
  return *reinterpret_cast<unsigned short*>(&h);
}

// ---------------- fused fp32 -> bf16 convert ----------------
__global__ __launch_bounds__(256) void cvt_all(const float* __restrict__ x,
                                               const float* __restrict__ wq,
                                               const float* __restrict__ wk,
                                               const float* __restrict__ wv,
                                               const float* __restrict__ wo,
                                               unsigned short* __restrict__ xb,
                                               unsigned short* __restrict__ wqkv,
                                               unsigned short* __restrict__ wob) {
  const int NX = 2097152, NQ = 524288, NK = 262144, NV = 262144, NO = 524288;
  const int T = NX + NQ + NK + NV + NO;
  int stride = gridDim.x * blockDim.x;
  for (int i = blockIdx.x * blockDim.x + threadIdx.x; i < T; i += stride) {
    const float* s;
    unsigned short* d;
    int j = i;
    if (j < NX) { s = x; d = xb; }
    else if ((j -= NX) < NQ) { s = wq; d = wqkv; }
    else if ((j -= NQ) < NK) { s = wk; d = wqkv + (size_t)NQ * 8; }
    else if ((j -= NK) < NV) { s = wv; d = wqkv + (size_t)(NQ + NK) * 8; }
    else { j -= NV; s = wo; d = wob; }
    const float4 a = *(const float4*)(s + (size_t)j * 8);
    const float4 b = *(const float4*)(s + (size_t)j * 8 + 4);
    ushort8 o;
    o[0] = f2bf(a.x); o[1] = f2bf(a.y); o[2] = f2bf(a.z); o[3] = f2bf(a.w);
    o[4] = f2bf(b.x); o[5] = f2bf(b.y); o[6] = f2bf(b.z); o[7] = f2bf(b.w);
    *(ushort8*)(d + (size_t)j * 8) = o;
  }
}

__device__ __forceinline__ void storeC(float* C, size_t i, float v) { C[i] = v; }
__device__ __forceinline__ void storeC(bf16* C, size_t i, float v) { C[i] = __float2bfloat16(v); }

// ---------------- 256x256 8-phase GEMM (unchanged) ----------------
#define LDA_(MI, BUF)                                                          \
  _Pragma("unroll") for (int rf = 0; rf < 4; ++rf)                             \
  _Pragma("unroll") for (int k = 0; k < 2; ++k) {                              \
    const int row_ = (MI * 4 + rf) * 16 + lr;                                  \
    a[rf][k] = *(const bf16x8*)&sA[BUF][wm][row_][((k * 4 + lg) ^ (row_ & 7)) * 8]; \
  }
#define LDB_(NI, BUF, BREG)                                                    \
  _Pragma("unroll") for (int j = 0; j < 2; ++j)                                \
  _Pragma("unroll") for (int k = 0; k < 2; ++k) {                              \
    const int row_ = (bco + NI * 2 + j) * 16 + lr;                             \
    BREG[j][k] = *(const bf16x8*)&sB[BUF][bh][row_][((k * 4 + lg) ^ (row_ & 7)) * 8]; \
  }
#define MM_(MI, NI, BREG)                                                      \
  __builtin_amdgcn_s_setprio(1);                                               \
  _Pragma("unroll") for (int rf = 0; rf < 4; ++rf)                             \
  _Pragma("unroll") for (int j = 0; j < 2; ++j)                                \
  _Pragma("unroll") for (int k = 0; k < 2; ++k)                                \
    acc[MI * 4 + rf][NI * 2 + j] =                                             \
        MFMA16(a[rf][k], BREG[j][k], acc[MI * 4 + rf][NI * 2 + j]);            \
  __builtin_amdgcn_s_setprio(0);
#define BAR_ __builtin_amdgcn_s_barrier();
#define VM4_ asm volatile("s_waitcnt vmcnt(4)" ::: "memory");
#define VM0_ asm volatile("s_waitcnt vmcnt(0)" ::: "memory");

template <typename OUT_T>
__global__ __launch_bounds__(512, 2) void gemm8(const bf16* __restrict__ A,
                                                const bf16* __restrict__ B,
                                                OUT_T* __restrict__ C,
                                                int M, int N, int K,
                                                int gm, int gn, int rbm, int rbn) {
  const int nwg = gridDim.x;
  const int cpx = nwg >> 3;
  const int swz = (blockIdx.x & 7) * cpx + (blockIdx.x >> 3);
  const int rsz = rbm * rbn;
  const int region = swz / rsz, rid = swz % rsz;
  const int regions_n = gn / rbn;
  const int bm = (region / regions_n) * rbm + rid / rbn;
  const int bn = (region % regions_n) * rbn + rid % rbn;

  __shared__ __align__(16) bf16 sA[2][2][128][64];
  __shared__ __align__(16) bf16 sB[2][2][128][64];

  const int tid = threadIdx.x;
  const int lane = tid & 63;
  const int wave = tid >> 6;
  const int wm = wave >> 2;
  const int wn = wave & 3;
  const int lg = lane >> 4, lr = lane & 15;
  const int bh = wn >> 1;
  const int bco = (wn & 1) * 4;

  const int rowA = bm * 256;
  const int colB = bn * 256;
  const int NT = K >> 6;

  f32x4 acc[8][4];
  #pragma unroll
  for (int i = 0; i < 8; ++i)
    #pragma unroll
    for (int j = 0; j < 4; ++j) acc[i][j] = (f32x4){0.f, 0.f, 0.f, 0.f};

  auto stA = [&](int buf, int half, int kt) {
    const bf16* src = A + (size_t)(rowA + half * 128) * K + kt * 64;
    #pragma unroll
    for (int is = 0; is < 2; ++is) {
      int r = is * 64 + (tid >> 3);
      int sl = (tid & 7) ^ (r & 7);
      gl_lds16(src + (size_t)r * K + sl * 8, &sA[buf][half][r][(tid & 7) * 8]);
    }
  };
  auto stB = [&](int buf, int half, int kt) {
    const bf16* src = B + (size_t)(colB + half * 128) * K + kt * 64;
    #pragma unroll
    for (int is = 0; is < 2; ++is) {
      int r = is * 64 + (tid >> 3);
      int sl = (tid & 7) ^ (r & 7);
      gl_lds16(src + (size_t)r * K + sl * 8, &sB[buf][half][r][(tid & 7) * 8]);
    }
  };

  stB(0, 0, 0); stB(0, 1, 0); stA(0, 0, 0); stA(0, 1, 0);
  stB(1, 0, 1); stB(1, 1, 1);
  VM4_
  __builtin_amdgcn_s_barrier();

  for (int t = 0; t < NT; t += 2) {
    const bool lastit = (t + 2 >= NT);
    bf16x8 a[4][2], bl[2][2], br[2][2];
    // ---------- K-tile t (buf0) ----------
    LDA_(0, 0) LDB_(0, 0, bl)
    stA(1, 0, t + 1);
    BAR_ MM_(0, 0, bl) BAR_
    LDB_(1, 0, br)
    stA(1, 1, t + 1);
    BAR_ MM_(0, 1, br) BAR_
    LDA_(1, 0)
    if (!lastit) stB(0, 0, t + 2);
    BAR_ MM_(1, 0, bl) BAR_
    if (!lastit) stB(0, 1, t + 2);
    BAR_ MM_(1, 1, br)
    if (lastit) { VM0_ } else { VM4_ }
    BAR_
    // ---------- K-tile t+1 (buf1) ----------
    LDA_(0, 1) LDB_(0, 1, bl)
    if (!lastit) stA(0, 0, t + 2);
    BAR_ MM_(0, 0, bl) BAR_
    LDB_(1, 1, br)
    if (!lastit) stA(0, 1, t + 2);
    BAR_ MM_(0, 1, br) BAR_
    LDA_(1, 1)
    if (t + 3 < NT) stB(1, 0, t + 3);
    BAR_ MM_(1, 0, bl) BAR_
    if (t + 3 < NT) stB(1, 1, t + 3);
    BAR_ MM_(1, 1, br)
    if (!lastit) { VM4_ }
    BAR_
  }

  #pragma unroll
  for (int rf = 0; rf < 8; ++rf)
    #pragma unroll
    for (int cf = 0; cf < 4; ++cf)
      #pragma unroll
      for (int r = 0; r < 4; ++r) {
        size_t row = rowA + wm * 128 + rf * 16 + lg * 4 + r;
        size_t col = colB + wn * 64 + cf * 16 + lr;
        storeC(C, row * (size_t)N + col, acc[rf][cf][r]);
      }
}

// ---------------- RMSNorm + RoPE on Q and K (Q pre-scaled by 1/sqrt(D)*log2e) ----------------
__global__ __launch_bounds__(256) void norm_rope(const bf16* __restrict__ qkv,
                                                 const float* __restrict__ cosT,
                                                 const float* __restrict__ sinT,
                                                 const float* __restrict__ qw,
                                                 const float* __restrict__ kw,
                                                 bf16* __restrict__ Qn, bf16* __restrict__ Kn) {
  const int bs = blockIdx.x;
  const int s = bs & (Sc - 1);
  const int b = bs >> 11;
  const int wave = threadIdx.x >> 6, lane = threadIdx.x & 63;
  const float QSCL = 0.08838834764831845f * 1.4426950408889634f;
  const float c0 = cosT[(size_t)s * Dc + lane];
  const float c1 = cosT[(size_t)s * Dc + 64 + lane];
  const float s0 = sinT[(size_t)s * Dc + lane];
  const float s1 = sinT[(size_t)s * Dc + 64 + lane];
  const bf16* row = qkv + (size_t)bs * 4096;
  #pragma unroll
  for (int i = 0; i < 6; ++i) {
    int head = wave * 6 + i;
    bool isQ = head < 16;
    int col = head * Dc;
    float x0 = __bfloat162float(row[col + lane]);
    float x1 = __bfloat162float(row[col + 64 + lane]);
    float ss = x0 * x0 + x1 * x1;
    #pragma unroll
    for (int off = 32; off; off >>= 1) ss += __shfl_xor(ss, off);
    float inv = rsqrtf(ss * (1.0f / 128.0f) + 1e-6f);
    const float* w = isQ ? qw : kw;
    float n0 = x0 * inv * w[lane];
    float n1 = x1 * inv * w[lane + 64];
    float o0 = n0 * c0 - n1 * s0;
    float o1 = n1 * c1 + n0 * s1;
    if (isQ) { o0 *= QSCL; o1 *= QSCL; }
    size_t base;
    bf16* dst;
    if (isQ) { base = ((size_t)(b * Hc + head) * Sc + s) * Dc; dst = Qn; }
    else     { base = ((size_t)(b * KVc + (head - 16)) * Sc + s) * Dc; dst = Kn; }
    dst[base + lane] = __float2bfloat16(o0);
    dst[base + 64 + lane] = __float2bfloat16(o1);
  }
}

// ---------------- V transpose: qkv V slice -> Vt [B][KV][D][S] ----------------
__global__ __launch_bounds__(256) void v_transpose(const bf16* __restrict__ qkv,
                                                   bf16* __restrict__ Vt) {
  const int s0 = blockIdx.x * 64;
  const int bk = blockIdx.y;
  __shared__ __align__(16) bf16 tile[64][136];
  const int tid = threadIdx.x;
  const size_t srcbase = ((size_t)(bk >> 3) * Sc + s0) * 4096 + 3072 + (size_t)(bk & 7) * Dc;
  #pragma unroll
  for (int it = 0; it < 4; ++it) {
    int idx = it * 256 + tid;
    int r = idx >> 4, ch = idx & 15;
    *(bf16x8*)&tile[r][ch * 8] = *(const bf16x8*)(qkv + srcbase + (size_t)r * 4096 + ch * 8);
  }
  __syncthreads();
  const size_t dstbase = (size_t)bk * Dc * Sc + s0;
  #pragma unroll
  for (int it = 0; it < 4; ++it) {
    int idx = it * 256 + tid;
    int d = idx >> 3, scc = idx & 7;
    bf16x8 o;
    #pragma unroll
    for (int j = 0; j < 8; ++j) o[j] = *(const short*)&tile[scc * 8 + j][d];
    *(bf16x8*)(Vt + dstbase + (size_t)d * Sc + scc * 8) = o;
  }
}

// ---------------- causal GQA flash attention ----------------
// T3-minimum double-buffer with STATIC buffers (gemm8's discipline): issue stage(t+1)
// before compute(t); asm vmcnt(0) AFTER compute (latency hidden); raw s_barrier,
// ONE barrier per tile. Swapped QK^T in-lane softmax, T2 swizzle, heavy-first, T5, T13.
// LDS budget: 32K(Kx2)+32K(Vx2)+16K(sP, pad dropped) = exactly 80KB -> 2 blocks/CU.
__global__ __launch_bounds__(512, 4) void flash_kernel(const bf16* __restrict__ Qn,
                                                       const bf16* __restrict__ Kn,
                                                       const bf16* __restrict__ Vt,
                                                       bf16* __restrict__ Out) {
  const int qi = 15 - (blockIdx.x >> 6);
  const int bh = blockIdx.x & 63;
  const int q0 = qi * 128;
  const int b = bh >> 4, h = bh & 15;
  const int kv = h >> 1;
  const int tid = threadIdx.x;
  const int wave = tid >> 6, lane = tid & 63;
  const int lg = lane >> 4, lr = lane & 15;
  const int rm = lr & 7;

  __shared__ __align__(16) bf16 sK0[64][128];
  __shared__ __align__(16) bf16 sK1[64][128];
  __shared__ __align__(16) bf16 sV0[128][64];
  __shared__ __align__(16) bf16 sV1[128][64];
  __shared__ __align__(16) unsigned short sP[8][16][64];  // [wave][q=lr][k], XOR-swizzled blocks

  const int qrow = q0 + wave * 16;
  const bf16* qbase = Qn + ((size_t)(b * Hc + h) * Sc + qrow + lr) * Dc;
  bf16x8 qf[4];
  #pragma unroll
  for (int kk = 0; kk < 4; ++kk) qf[kk] = *(const bf16x8*)(qbase + kk * 32 + lg * 8);

  f32x4 oacc[8];
  #pragma unroll
  for (int i = 0; i < 8; ++i) oacc[i] = (f32x4){0.f, 0.f, 0.f, 0.f};
  float m_run = -3.0e38f, l_run = 0.f;   // per-lane scalars: this lane's q-row = qrow+lr

  const bf16* kb = Kn + ((size_t)(b * KVc + kv) * Sc) * Dc;
  const bf16* vb = Vt + ((size_t)(b * KVc + kv) * Dc) * Sc;
  const int nt = 2 * qi + 2;

  auto STAGE = [&](bf16 (*sKb)[128], bf16 (*sVb)[64], int t) {
    const int k0 = t * 64;
    #pragma unroll
    for (int it = 0; it < 2; ++it) {
      int idx = it * 512 + tid;
      int r = idx >> 4, ps = idx & 15;
      int ls = ps ^ (r & 7);
      gl_lds16(kb + (size_t)(k0 + r) * Dc + ls * 8, &sKb[r][ps * 8]);
    }
    #pragma unroll
    for (int it = 0; it < 2; ++it) {
      int idx = it * 512 + tid;
      int r = idx >> 3, ps = idx & 7;
      int ls = ps ^ (r & 7);
      gl_lds16(vb + (size_t)r * Sc + k0 + ls * 8, &sVb[r][ps * 8]);
    }
  };

  auto COMPUTE = [&](const bf16 (*sKb)[128], const bf16 (*sVb)[64], int t) {
    const int k0 = t * 64;
    // QK^T swapped: tt[c][r] = S[q=qrow+lr][k = k0 + c*16 + lg*4 + r]
    float tt[4][4];
    const int qg = qrow + lr;
    __builtin_amdgcn_s_setprio(1);
    #pragma unroll
    for (int c = 0; c < 4; ++c) {
      f32x4 sacc = (f32x4){0.f, 0.f, 0.f, 0.f};
      #pragma unroll
      for (int kk = 0; kk < 4; ++kk) {
        bf16x8 kf = *(const bf16x8*)&sKb[c * 16 + lr][((kk * 4 + lg) ^ rm) * 8];
        sacc = MFMA16(kf, qf[kk], sacc);   // A=K, B=Q -> D[k][q]
      }
      if (k0 + c * 16 + 15 <= qrow) {      // wave-uniform: fully unmasked quadrant
        #pragma unroll
        for (int r = 0; r < 4; ++r) tt[c][r] = sacc[r];
      } else {
        #pragma unroll
        for (int r = 0; r < 4; ++r) {
          int kg = k0 + c * 16 + lg * 4 + r;
          tt[c][r] = (kg <= qg) ? sacc[r] : -3.0e38f;
        }
      }
    }
    __builtin_amdgcn_s_setprio(0);

    // in-lane row max + 2 cross-half shfls
    float m0 = fmaxf(fmaxf(tt[0][0], tt[0][1]), fmaxf(tt[0][2], tt[0][3]));
    float m1 = fmaxf(fmaxf(tt[1][0], tt[1][1]), fmaxf(tt[1][2], tt[1][3]));
    float m2 = fmaxf(fmaxf(tt[2][0], tt[2][1]), fmaxf(tt[2][2], tt[2][3]));
    float m3 = fmaxf(fmaxf(tt[3][0], tt[3][1]), fmaxf(tt[3][2], tt[3][3]));
    float mx = fmaxf(fmaxf(m0, m1), fmaxf(m2, m3));
    mx = fmaxf(mx, __shfl_xor(mx, 16));
    mx = fmaxf(mx, __shfl_xor(mx, 32));

    bool grow = mx > m_run + 8.f;   // T13 defer-max
    if (__any(grow)) {
      float mnew = fmaxf(m_run, mx);
      float alpha = exp2f(m_run - mnew);
      m_run = mnew;
      l_run *= alpha;
      float a0 = __shfl(alpha, lg * 4 + 0);
      float a1 = __shfl(alpha, lg * 4 + 1);
      float a2 = __shfl(alpha, lg * 4 + 2);
      float a3 = __shfl(alpha, lg * 4 + 3);
      #pragma unroll
      for (int dc = 0; dc < 8; ++dc) {
        oacc[dc][0] *= a0; oacc[dc][1] *= a1; oacc[dc][2] *= a2; oacc[dc][3] *= a3;
      }
    }
    float lsum = 0.f;
    #pragma unroll
    for (int c = 0; c < 4; ++c)
      #pragma unroll
      for (int r = 0; r < 4; ++r) { tt[c][r] = exp2f(tt[c][r] - m_run); lsum += tt[c][r]; }
    l_run += lsum;

    // P write: pack r-pairs as b32, 16B-block XOR swizzle matching the b128 read
    #pragma unroll
    for (int c = 0; c < 4; ++c)
      #pragma unroll
      for (int r2 = 0; r2 < 2; ++r2) {
        int col = c * 16 + lg * 4 + 2 * r2;
        int colx = (((col >> 3) ^ rm) << 3) + (col & 7);
        ushort2 w;
        w.x = f2bf(tt[c][2 * r2]);
        w.y = f2bf(tt[c][2 * r2 + 1]);
        *(ushort2*)&sP[wave][lr][colx] = w;
      }

    __builtin_amdgcn_s_setprio(1);
    #pragma unroll
    for (int kk2 = 0; kk2 < 2; ++kk2) {
      bf16x8 pf = *(const bf16x8*)&sP[wave][lr][((kk2 * 4 + lg) ^ rm) * 8];
      #pragma unroll
      for (int dc = 0; dc < 8; ++dc) {
        bf16x8 vf = *(const bf16x8*)&sVb[dc * 16 + lr][((kk2 * 4 + lg) ^ rm) * 8];
        oacc[dc] = MFMA16(pf, vf, oacc[dc]);
      }
    }
    __builtin_amdgcn_s_setprio(0);
  };

  // prologue: stage tile 0 into buf0
  STAGE(sK0, sV0, 0);
  VM0_
  __builtin_amdgcn_s_barrier();

  int t = 0;
  while (true) {
    // even tile: compute buf0, prefetch into buf1
    if (t + 1 < nt) STAGE(sK1, sV1, t + 1);
    COMPUTE(sK0, sV0, t);
    VM0_                                  // prefetch landed (latency hidden under compute)
    __builtin_amdgcn_s_barrier();         // all waves done reading buf0; buf1 visible
    if (++t >= nt) break;
    // odd tile: compute buf1, prefetch into buf0
    if (t + 1 < nt) STAGE(sK0, sV0, t + 1);
    COMPUTE(sK1, sV1, t);
    VM0_
    __builtin_amdgcn_s_barrier();
    if (++t >= nt) break;
  }

  float l = l_run;
  l += __shfl_xor(l, 16);
  l += __shfl_xor(l, 32);
  float linv = 1.f / l;
  float li0 = __shfl(linv, lg * 4 + 0);
  float li1 = __shfl(linv, lg * 4 + 1);
  float li2 = __shfl(linv, lg * 4 + 2);
  float li3 = __shfl(linv, lg * 4 + 3);
  #pragma unroll
  for (int dc = 0; dc < 8; ++dc) {
    size_t rowb = (size_t)b * Sc + qrow + lg * 4;
    size_t colb = (size_t)h * Dc + dc * 16 + lr;
    Out[(rowb + 0) * (size_t)(Hc * Dc) + colb] = __float2bfloat16(oacc[dc][0] * li0);
    Out[(rowb + 1) * (size_t)(Hc * Dc) + colb] = __float2bfloat16(oacc[dc][1] * li1);
    Out[(rowb + 2) * (size_t)(Hc * Dc) + colb] = __float2bfloat16(oacc[dc][2] * li2);
    Out[(rowb + 3) * (size_t)(Hc * Dc) + colb] = __float2bfloat16(oacc[dc][3] * li3);
  }
}

// ---------------- launch ----------------
extern "C" void kernel_launch(void* const* d_in, const int* in_sizes, int n_in,
                              void* d_out, int out_size, void* d_ws, size_t ws_size,
                              hipStream_t stream) {
  const float* x    = (const float*)d_in[0];
  const float* cosT = (const float*)d_in[1];
  const float* sinT = (const float*)d_in[2];
  const float* wq   = (const float*)d_in[3];
  const float* wk   = (const float*)d_in[4];
  const float* wv   = (const float*)d_in[5];
  const float* wo   = (const float*)d_in[6];
  const float* qnw  = (const float*)d_in[7];
  const float* knw  = (const float*)d_in[8];
  float* out = (float*)d_out;

  const size_t MB = 1ull << 20;
  char* ws = (char*)d_ws;
  bf16* xb   = (bf16*)(ws + 0);        // 32MB  [8192][2048]
  bf16* wqkv = (bf16*)(ws + 32 * MB);  // 16MB  [4096][2048]
  bf16* wob  = (bf16*)(ws + 48 * MB);  // 8MB   [2048][2048]
  bf16* qkv  = (bf16*)(ws + 56 * MB);  // 64MB  [8192][4096]
  bf16* Qn   = (bf16*)(ws + 120 * MB); // 32MB  [B][H][S][D]
  bf16* Kn   = (bf16*)(ws + 152 * MB); // 16MB  [B][KV][S][D]
  bf16* Vt   = (bf16*)(ws + 168 * MB); // 16MB  [B][KV][D][S]
  bf16* attn = (bf16*)(ws + 184 * MB); // 32MB  [8192][2048]

  cvt_all<<<2048, 256, 0, stream>>>(x, wq, wk, wv, wo,
                                    (unsigned short*)xb, (unsigned short*)wqkv,
                                    (unsigned short*)wob);

  gemm8<bf16><<<512, 512, 0, stream>>>(xb, wqkv, qkv, 8192, 4096, 2048, 32, 16, 16, 4);
  norm_rope<<<8192, 256, 0, stream>>>(qkv, cosT, sinT, qnw, knw, Qn, Kn);
  v_transpose<<<dim3(32, 32), 256, 0, stream>>>(qkv, Vt);
  flash_kernel<<<1024, 512, 0, stream>>>(Qn, Kn, Vt, attn);
  gemm8<float><<<256, 512, 0, stream>>>(attn, wob, out, 8192, 2048, 2048, 32, 8, 8, 4);
}

// Round 11
// 362.652 us; speedup vs baseline: 1.1311x; 1.0037x over previous
//
#include <hip/hip_runtime.h>
#include <hip/hip_bf16.h>
#include <stdint.h>

using bf16 = __hip_bfloat16;
typedef __attribute__((ext_vector_type(8))) short bf16x8;
typedef __attribute__((ext_vector_type(4))) float f32x4;
typedef __attribute__((ext_vector_type(8))) unsigned short ushort8;

#define MFMA16(a,b,c) __builtin_amdgcn_mfma_f32_16x16x32_bf16(a,b,c,0,0,0)

static constexpr int Bc = 4, Sc = 2048, HSc = 2048, Hc = 16, KVc = 8, Dc = 128;

__device__ __forceinline__ void gl_lds16(const void* g, void* l) {
  __builtin_amdgcn_global_load_lds((const __attribute__((address_space(1))) uint32_t*)g,
                                   (__attribute__((address_space(3))) uint32_t*)l, 16, 0, 0);
}

__device__ __forceinline__ unsigned short f2bf(float f) {
  bf16 h = __float2bfloat16(f);
  return *reinterpret_cast<unsigned short*>(&h);
}

// ---------------- fp32 -> bf16 convert: statically block-partitioned regions ----------------
__global__ __launch_bounds__(256) void cvt_all(const float* __restrict__ x,
                                               const float* __restrict__ wq,
                                               const float* __restrict__ wk,
                                               const float* __restrict__ wv,
                                               const float* __restrict__ wo,
                                               unsigned short* __restrict__ xb,
                                               unsigned short* __restrict__ wqkv,
                                               unsigned short* __restrict__ wob) {
  const int NX = 2097152, NQ = 524288, NK = 262144, NV = 262144, NO = 524288;
  const float* s;
  unsigned short* d;
  int n, rb, nb;
  const int bid = blockIdx.x;
  if (bid < 1170)      { s = x;  d = xb;                       n = NX; rb = bid;        nb = 1170; }
  else if (bid < 1463) { s = wq; d = wqkv;                     n = NQ; rb = bid - 1170; nb = 293; }
  else if (bid < 1609) { s = wk; d = wqkv + (size_t)NQ * 8;    n = NK; rb = bid - 1463; nb = 146; }
  else if (bid < 1755) { s = wv; d = wqkv + (size_t)(NQ + NK) * 8; n = NV; rb = bid - 1609; nb = 146; }
  else                 { s = wo; d = wob;                      n = NO; rb = bid - 1755; nb = 293; }
  const int stride = nb * 256;
  for (int i = rb * 256 + threadIdx.x; i < n; i += stride) {
    const float4 a = *(const float4*)(s + (size_t)i * 8);
    const float4 b = *(const float4*)(s + (size_t)i * 8 + 4);
    ushort8 o;
    o[0] = f2bf(a.x); o[1] = f2bf(a.y); o[2] = f2bf(a.z); o[3] = f2bf(a.w);
    o[4] = f2bf(b.x); o[5] = f2bf(b.y); o[6] = f2bf(b.z); o[7] = f2bf(b.w);
    *(ushort8*)(d + (size_t)i * 8) = o;
  }
}

__device__ __forceinline__ void storeC(float* C, size_t i, float v) { C[i] = v; }
__device__ __forceinline__ void storeC(bf16* C, size_t i, float v) { C[i] = __float2bfloat16(v); }

// ---------------- 256x256 8-phase GEMM: + hoisted stage pointers, + lgkmcnt(8) pacing ----------------
#define LDA_(MI, BUF)                                                          \
  _Pragma("unroll") for (int rf = 0; rf < 4; ++rf)                             \
  _Pragma("unroll") for (int k = 0; k < 2; ++k) {                              \
    const int row_ = (MI * 4 + rf) * 16 + lr;                                  \
    a[rf][k] = *(const bf16x8*)&sA[BUF][wm][row_][((k * 4 + lg) ^ (row_ & 7)) * 8]; \
  }
#define LDB_(NI, BUF, BREG)                                                    \
  _Pragma("unroll") for (int j = 0; j < 2; ++j)                                \
  _Pragma("unroll") for (int k = 0; k < 2; ++k) {                              \
    const int row_ = (bco + NI * 2 + j) * 16 + lr;                             \
    BREG[j][k] = *(const bf16x8*)&sB[BUF][bh][row_][((k * 4 + lg) ^ (row_ & 7)) * 8]; \
  }
#define MM_(MI, NI, BREG)                                                      \
  __builtin_amdgcn_s_setprio(1);                                               \
  _Pragma("unroll") for (int rf = 0; rf < 4; ++rf)                             \
  _Pragma("unroll") for (int j = 0; j < 2; ++j)                                \
  _Pragma("unroll") for (int k = 0; k < 2; ++k)                                \
    acc[MI * 4 + rf][NI * 2 + j] =                                             \
        MFMA16(a[rf][k], BREG[j][k], acc[MI * 4 + rf][NI * 2 + j]);            \
  __builtin_amdgcn_s_setprio(0);
#define BAR_ __builtin_amdgcn_s_barrier();
#define VM4_ asm volatile("s_waitcnt vmcnt(4)" ::: "memory");
#define VM0_ asm volatile("s_waitcnt vmcnt(0)" ::: "memory");
#define LK8_ asm volatile("s_waitcnt lgkmcnt(8)" ::: "memory");

template <typename OUT_T>
__global__ __launch_bounds__(512, 2) void gemm8(const bf16* __restrict__ A,
                                                const bf16* __restrict__ B,
                                                OUT_T* __restrict__ C,
                                                int M, int N, int K,
                                                int gm, int gn, int rbm, int rbn) {
  const int nwg = gridDim.x;
  const int cpx = nwg >> 3;
  const int swz = (blockIdx.x & 7) * cpx + (blockIdx.x >> 3);
  const int rsz = rbm * rbn;
  const int region = swz / rsz, rid = swz % rsz;
  const int regions_n = gn / rbn;
  const int bm = (region / regions_n) * rbm + rid / rbn;
  const int bn = (region % regions_n) * rbn + rid % rbn;

  __shared__ __align__(16) bf16 sA[2][2][128][64];
  __shared__ __align__(16) bf16 sB[2][2][128][64];

  const int tid = threadIdx.x;
  const int lane = tid & 63;
  const int wave = tid >> 6;
  const int wm = wave >> 2;
  const int wn = wave & 3;
  const int lg = lane >> 4, lr = lane & 15;
  const int bh = wn >> 1;
  const int bco = (wn & 1) * 4;

  const int rowA = bm * 256;
  const int colB = bn * 256;
  const int NT = K >> 6;

  f32x4 acc[8][4];
  #pragma unroll
  for (int i = 0; i < 8; ++i)
    #pragma unroll
    for (int j = 0; j < 4; ++j) acc[i][j] = (f32x4){0.f, 0.f, 0.f, 0.f};

  // hoisted per-thread staging geometry (rows/slots loop-invariant; half/is literal at call sites)
  const int rS = tid >> 3;                       // row within each 64-row chunk
  const int sl8 = ((tid & 7) ^ (rS & 7)) * 8;    // inverse-swizzled source slot (elements)
  const int ch8 = (tid & 7) * 8;                 // linear LDS dest slot (elements)
  const bf16* pA = A + (size_t)(rowA + rS) * K + sl8;
  const bf16* pB = B + (size_t)(colB + rS) * K + sl8;
  const size_t h128 = (size_t)128 * K;           // half offset (elements)
  const size_t is64 = (size_t)64 * K;            // is offset (elements)

  auto stA = [&](int buf, int half, int kt) {
    const bf16* base = pA + (size_t)half * h128 + (size_t)kt * 64;
    gl_lds16(base,        &sA[buf][half][rS][ch8]);
    gl_lds16(base + is64, &sA[buf][half][rS + 64][ch8]);
  };
  auto stB = [&](int buf, int half, int kt) {
    const bf16* base = pB + (size_t)half * h128 + (size_t)kt * 64;
    gl_lds16(base,        &sB[buf][half][rS][ch8]);
    gl_lds16(base + is64, &sB[buf][half][rS + 64][ch8]);
  };

  stB(0, 0, 0); stB(0, 1, 0); stA(0, 0, 0); stA(0, 1, 0);
  stB(1, 0, 1); stB(1, 1, 1);
  VM4_
  __builtin_amdgcn_s_barrier();

  for (int t = 0; t < NT; t += 2) {
    const bool lastit = (t + 2 >= NT);
    bf16x8 a[4][2], bl[2][2], br[2][2];
    // ---------- K-tile t (buf0) ----------
    LDA_(0, 0) LDB_(0, 0, bl)
    stA(1, 0, t + 1);
    LK8_
    BAR_ MM_(0, 0, bl) BAR_
    LDB_(1, 0, br)
    stA(1, 1, t + 1);
    BAR_ MM_(0, 1, br) BAR_
    LDA_(1, 0)
    if (!lastit) stB(0, 0, t + 2);
    BAR_ MM_(1, 0, bl) BAR_
    if (!lastit) stB(0, 1, t + 2);
    BAR_ MM_(1, 1, br)
    if (lastit) { VM0_ } else { VM4_ }
    BAR_
    // ---------- K-tile t+1 (buf1) ----------
    LDA_(0, 1) LDB_(0, 1, bl)
    if (!lastit) stA(0, 0, t + 2);
    LK8_
    BAR_ MM_(0, 0, bl) BAR_
    LDB_(1, 1, br)
    if (!lastit) stA(0, 1, t + 2);
    BAR_ MM_(0, 1, br) BAR_
    LDA_(1, 1)
    if (t + 3 < NT) stB(1, 0, t + 3);
    BAR_ MM_(1, 0, bl) BAR_
    if (t + 3 < NT) stB(1, 1, t + 3);
    BAR_ MM_(1, 1, br)
    if (!lastit) { VM4_ }
    BAR_
  }

  #pragma unroll
  for (int rf = 0; rf < 8; ++rf)
    #pragma unroll
    for (int cf = 0; cf < 4; ++cf)
      #pragma unroll
      for (int r = 0; r < 4; ++r) {
        size_t row = rowA + wm * 128 + rf * 16 + lg * 4 + r;
        size_t col = colB + wn * 64 + cf * 16 + lr;
        storeC(C, row * (size_t)N + col, acc[rf][cf][r]);
      }
}

// ---------------- RMSNorm + RoPE on Q and K (Q pre-scaled by 1/sqrt(D)*log2e) ----------------
__global__ __launch_bounds__(256) void norm_rope(const bf16* __restrict__ qkv,
                                                 const float* __restrict__ cosT,
                                                 const float* __restrict__ sinT,
                                                 const float* __restrict__ qw,
                                                 const float* __restrict__ kw,
                                                 bf16* __restrict__ Qn, bf16* __restrict__ Kn) {
  const int bs = blockIdx.x;
  const int s = bs & (Sc - 1);
  const int b = bs >> 11;
  const int wave = threadIdx.x >> 6, lane = threadIdx.x & 63;
  const float QSCL = 0.08838834764831845f * 1.4426950408889634f;
  const float c0 = cosT[(size_t)s * Dc + lane];
  const float c1 = cosT[(size_t)s * Dc + 64 + lane];
  const float s0 = sinT[(size_t)s * Dc + lane];
  const float s1 = sinT[(size_t)s * Dc + 64 + lane];
  const bf16* row = qkv + (size_t)bs * 4096;
  #pragma unroll
  for (int i = 0; i < 6; ++i) {
    int head = wave * 6 + i;
    bool isQ = head < 16;
    int col = head * Dc;
    float x0 = __bfloat162float(row[col + lane]);
    float x1 = __bfloat162float(row[col + 64 + lane]);
    float ss = x0 * x0 + x1 * x1;
    #pragma unroll
    for (int off = 32; off; off >>= 1) ss += __shfl_xor(ss, off);
    float inv = rsqrtf(ss * (1.0f / 128.0f) + 1e-6f);
    const float* w = isQ ? qw : kw;
    float n0 = x0 * inv * w[lane];
    float n1 = x1 * inv * w[lane + 64];
    float o0 = n0 * c0 - n1 * s0;
    float o1 = n1 * c1 + n0 * s1;
    if (isQ) { o0 *= QSCL; o1 *= QSCL; }
    size_t base;
    bf16* dst;
    if (isQ) { base = ((size_t)(b * Hc + head) * Sc + s) * Dc; dst = Qn; }
    else     { base = ((size_t)(b * KVc + (head - 16)) * Sc + s) * Dc; dst = Kn; }
    dst[base + lane] = __float2bfloat16(o0);
    dst[base + 64 + lane] = __float2bfloat16(o1);
  }
}

// ---------------- V transpose: qkv V slice -> Vt [B][KV][D][S] ----------------
__global__ __launch_bounds__(256) void v_transpose(const bf16* __restrict__ qkv,
                                                   bf16* __restrict__ Vt) {
  const int s0 = blockIdx.x * 64;
  const int bk = blockIdx.y;
  __shared__ __align__(16) bf16 tile[64][136];
  const int tid = threadIdx.x;
  const size_t srcbase = ((size_t)(bk >> 3) * Sc + s0) * 4096 + 3072 + (size_t)(bk & 7) * Dc;
  #pragma unroll
  for (int it = 0; it < 4; ++it) {
    int idx = it * 256 + tid;
    int r = idx >> 4, ch = idx & 15;
    *(bf16x8*)&tile[r][ch * 8] = *(const bf16x8*)(qkv + srcbase + (size_t)r * 4096 + ch * 8);
  }
  __syncthreads();
  const size_t dstbase = (size_t)bk * Dc * Sc + s0;
  #pragma unroll
  for (int it = 0; it < 4; ++it) {
    int idx = it * 256 + tid;
    int d = idx >> 3, scc = idx & 7;
    bf16x8 o;
    #pragma unroll
    for (int j = 0; j < 8; ++j) o[j] = *(const short*)&tile[scc * 8 + j][d];
    *(bf16x8*)(Vt + dstbase + (size_t)d * Sc + scc * 8) = o;
  }
}

// ---------------- causal GQA flash attention (round-10 structure, unchanged) ----------------
__global__ __launch_bounds__(512, 4) void flash_kernel(const bf16* __restrict__ Qn,
                                                       const bf16* __restrict__ Kn,
                                                       const bf16* __restrict__ Vt,
                                                       bf16* __restrict__ Out) {
  const int qi = 15 - (blockIdx.x >> 6);
  const int bh = blockIdx.x & 63;
  const int q0 = qi * 128;
  const int b = bh >> 4, h = bh & 15;
  const int kv = h >> 1;
  const int tid = threadIdx.x;
  const int wave = tid >> 6, lane = tid & 63;
  const int lg = lane >> 4, lr = lane & 15;
  const int rm = lr & 7;

  __shared__ __align__(16) bf16 sK0[64][128];
  __shared__ __align__(16) bf16 sK1[64][128];
  __shared__ __align__(16) bf16 sV0[128][64];
  __shared__ __align__(16) bf16 sV1[128][64];
  __shared__ __align__(16) unsigned short sP[8][16][64];

  const int qrow = q0 + wave * 16;
  const bf16* qbase = Qn + ((size_t)(b * Hc + h) * Sc + qrow + lr) * Dc;
  bf16x8 qf[4];
  #pragma unroll
  for (int kk = 0; kk < 4; ++kk) qf[kk] = *(const bf16x8*)(qbase + kk * 32 + lg * 8);

  f32x4 oacc[8];
  #pragma unroll
  for (int i = 0; i < 8; ++i) oacc[i] = (f32x4){0.f, 0.f, 0.f, 0.f};
  float m_run = -3.0e38f, l_run = 0.f;

  const bf16* kb = Kn + ((size_t)(b * KVc + kv) * Sc) * Dc;
  const bf16* vb = Vt + ((size_t)(b * KVc + kv) * Dc) * Sc;
  const int nt = 2 * qi + 2;

  auto STAGE = [&](bf16 (*sKb)[128], bf16 (*sVb)[64], int t) {
    const int k0 = t * 64;
    #pragma unroll
    for (int it = 0; it < 2; ++it) {
      int idx = it * 512 + tid;
      int r = idx >> 4, ps = idx & 15;
      int ls = ps ^ (r & 7);
      gl_lds16(kb + (size_t)(k0 + r) * Dc + ls * 8, &sKb[r][ps * 8]);
    }
    #pragma unroll
    for (int it = 0; it < 2; ++it) {
      int idx = it * 512 + tid;
      int r = idx >> 3, ps = idx & 7;
      int ls = ps ^ (r & 7);
      gl_lds16(vb + (size_t)r * Sc + k0 + ls * 8, &sVb[r][ps * 8]);
    }
  };

  auto COMPUTE = [&](const bf16 (*sKb)[128], const bf16 (*sVb)[64], int t) {
    const int k0 = t * 64;
    float tt[4][4];
    const int qg = qrow + lr;
    __builtin_amdgcn_s_setprio(1);
    #pragma unroll
    for (int c = 0; c < 4; ++c) {
      f32x4 sacc = (f32x4){0.f, 0.f, 0.f, 0.f};
      #pragma unroll
      for (int kk = 0; kk < 4; ++kk) {
        bf16x8 kf = *(const bf16x8*)&sKb[c * 16 + lr][((kk * 4 + lg) ^ rm) * 8];
        sacc = MFMA16(kf, qf[kk], sacc);
      }
      if (k0 + c * 16 + 15 <= qrow) {
        #pragma unroll
        for (int r = 0; r < 4; ++r) tt[c][r] = sacc[r];
      } else {
        #pragma unroll
        for (int r = 0; r < 4; ++r) {
          int kg = k0 + c * 16 + lg * 4 + r;
          tt[c][r] = (kg <= qg) ? sacc[r] : -3.0e38f;
        }
      }
    }
    __builtin_amdgcn_s_setprio(0);

    float m0 = fmaxf(fmaxf(tt[0][0], tt[0][1]), fmaxf(tt[0][2], tt[0][3]));
    float m1 = fmaxf(fmaxf(tt[1][0], tt[1][1]), fmaxf(tt[1][2], tt[1][3]));
    float m2 = fmaxf(fmaxf(tt[2][0], tt[2][1]), fmaxf(tt[2][2], tt[2][3]));
    float m3 = fmaxf(fmaxf(tt[3][0], tt[3][1]), fmaxf(tt[3][2], tt[3][3]));
    float mx = fmaxf(fmaxf(m0, m1), fmaxf(m2, m3));
    mx = fmaxf(mx, __shfl_xor(mx, 16));
    mx = fmaxf(mx, __shfl_xor(mx, 32));

    bool grow = mx > m_run + 8.f;
    if (__any(grow)) {
      float mnew = fmaxf(m_run, mx);
      float alpha = exp2f(m_run - mnew);
      m_run = mnew;
      l_run *= alpha;
      float a0 = __shfl(alpha, lg * 4 + 0);
      float a1 = __shfl(alpha, lg * 4 + 1);
      float a2 = __shfl(alpha, lg * 4 + 2);
      float a3 = __shfl(alpha, lg * 4 + 3);
      #pragma unroll
      for (int dc = 0; dc < 8; ++dc) {
        oacc[dc][0] *= a0; oacc[dc][1] *= a1; oacc[dc][2] *= a2; oacc[dc][3] *= a3;
      }
    }
    float lsum = 0.f;
    #pragma unroll
    for (int c = 0; c < 4; ++c)
      #pragma unroll
      for (int r = 0; r < 4; ++r) { tt[c][r] = exp2f(tt[c][r] - m_run); lsum += tt[c][r]; }
    l_run += lsum;

    #pragma unroll
    for (int c = 0; c < 4; ++c)
      #pragma unroll
      for (int r2 = 0; r2 < 2; ++r2) {
        int col = c * 16 + lg * 4 + 2 * r2;
        int colx = (((col >> 3) ^ rm) << 3) + (col & 7);
        ushort2 w;
        w.x = f2bf(tt[c][2 * r2]);
        w.y = f2bf(tt[c][2 * r2 + 1]);
        *(ushort2*)&sP[wave][lr][colx] = w;
      }

    __builtin_amdgcn_s_setprio(1);
    #pragma unroll
    for (int kk2 = 0; kk2 < 2; ++kk2) {
      bf16x8 pf = *(const bf16x8*)&sP[wave][lr][((kk2 * 4 + lg) ^ rm) * 8];
      #pragma unroll
      for (int dc = 0; dc < 8; ++dc) {
        bf16x8 vf = *(const bf16x8*)&sVb[dc * 16 + lr][((kk2 * 4 + lg) ^ rm) * 8];
        oacc[dc] = MFMA16(pf, vf, oacc[dc]);
      }
    }
    __builtin_amdgcn_s_setprio(0);
  };

  STAGE(sK0, sV0, 0);
  VM0_
  __builtin_amdgcn_s_barrier();

  int t = 0;
  while (true) {
    if (t + 1 < nt) STAGE(sK1, sV1, t + 1);
    COMPUTE(sK0, sV0, t);
    VM0_
    __builtin_amdgcn_s_barrier();
    if (++t >= nt) break;
    if (t + 1 < nt) STAGE(sK0, sV0, t + 1);
    COMPUTE(sK1, sV1, t);
    VM0_
    __builtin_amdgcn_s_barrier();
    if (++t >= nt) break;
  }

  float l = l_run;
  l += __shfl_xor(l, 16);
  l += __shfl_xor(l, 32);
  float linv = 1.f / l;
  float li0 = __shfl(linv, lg * 4 + 0);
  float li1 = __shfl(linv, lg * 4 + 1);
  float li2 = __shfl(linv, lg * 4 + 2);
  float li3 = __shfl(linv, lg * 4 + 3);
  #pragma unroll
  for (int dc = 0; dc < 8; ++dc) {
    size_t rowb = (size_t)b * Sc + qrow + lg * 4;
    size_t colb = (size_t)h * Dc + dc * 16 + lr;
    Out[(rowb + 0) * (size_t)(Hc * Dc) + colb] = __float2bfloat16(oacc[dc][0] * li0);
    Out[(rowb + 1) * (size_t)(Hc * Dc) + colb] = __float2bfloat16(oacc[dc][1] * li1);
    Out[(rowb + 2) * (size_t)(Hc * Dc) + colb] = __float2bfloat16(oacc[dc][2] * li2);
    Out[(rowb + 3) * (size_t)(Hc * Dc) + colb] = __float2bfloat16(oacc[dc][3] * li3);
  }
}

// ---------------- launch ----------------
extern "C" void kernel_launch(void* const* d_in, const int* in_sizes, int n_in,
                              void* d_out, int out_size, void* d_ws, size_t ws_size,
                              hipStream_t stream) {
  const float* x    = (const float*)d_in[0];
  const float* cosT = (const float*)d_in[1];
  const float* sinT = (const float*)d_in[2];
  const float* wq   = (const float*)d_in[3];
  const float* wk   = (const float*)d_in[4];
  const float* wv   = (const float*)d_in[5];
  const float* wo   = (const float*)d_in[6];
  const float* qnw  = (const float*)d_in[7];
  const float* knw  = (const float*)d_in[8];
  float* out = (float*)d_out;

  const size_t MB = 1ull << 20;
  char* ws = (char*)d_ws;
  bf16* xb   = (bf16*)(ws + 0);        // 32MB  [8192][2048]
  bf16* wqkv = (bf16*)(ws + 32 * MB);  // 16MB  [4096][2048]
  bf16* wob  = (bf16*)(ws + 48 * MB);  // 8MB   [2048][2048]
  bf16* qkv  = (bf16*)(ws + 56 * MB);  // 64MB  [8192][4096]
  bf16* Qn   = (bf16*)(ws + 120 * MB); // 32MB  [B][H][S][D]
  bf16* Kn   = (bf16*)(ws + 152 * MB); // 16MB  [B][KV][S][D]
  bf16* Vt   = (bf16*)(ws + 168 * MB); // 16MB  [B][KV][D][S]
  bf16* attn = (bf16*)(ws + 184 * MB); // 32MB  [8192][2048]

  cvt_all<<<2048, 256, 0, stream>>>(x, wq, wk, wv, wo,
                                    (unsigned short*)xb, (unsigned short*)wqkv,
                                    (unsigned short*)wob);

  gemm8<bf16><<<512, 512, 0, stream>>>(xb, wqkv, qkv, 8192, 4096, 2048, 32, 16, 16, 4);
  norm_rope<<<8192, 256, 0, stream>>>(qkv, cosT, sinT, qnw, knw, Qn, Kn);
  v_transpose<<<dim3(32, 32), 256, 0, stream>>>(qkv, Vt);
  flash_kernel<<<1024, 512, 0, stream>>>(Qn, Kn, Vt, attn);
  gemm8<float><<<256, 512, 0, stream>>>(attn, wob, out, 8192, 2048, 2048, 32, 8, 8, 4);
}